// Round 1
// baseline (4570.638 us; speedup 1.0000x reference)
//
#include <hip/hip_runtime.h>
#include <stdint.h>

// ---------------------------------------------------------------------------
// Decoder_72516227826046: hierarchical pointer-net decoder, bit-faithful JAX
// threefry PRNG + gumbel-max categorical, fp32 throughout.
// One block per batch element (512 blocks x 256 threads). All sequential
// decode logic lives inside the block; no inter-block communication.
// ---------------------------------------------------------------------------

#define PARTITIONABLE 1   // JAX jax_threefry_partitionable (new default). Flip to 0 for legacy mode.

#define NB    512
#define NCELL 12
#define NNODE 40
#define EDIM  128
#define THREADS 256

// output layout (all float32)
#define OFF_CLP  0                    // cell_log_prob [512]
#define OFF_NLP  512                  // node_log_prob [6144]
#define OFF_CRW  6656                 // cell_reward   [512]
#define OFF_NRW  7168                 // node_reward   [6144]
#define OFF_CACT 13312                // cell_action   [6144]
#define OFF_NACT 19456                // node_action   [245760]

// ---------------- threefry2x32 (bit-exact vs jax._src.prng) ----------------
__device__ __forceinline__ uint32_t rotl32(uint32_t x, int d) {
  return (x << d) | (x >> (32 - d));
}

__device__ __forceinline__ void tf2x32(uint32_t k0, uint32_t k1,
                                       uint32_t c0, uint32_t c1,
                                       uint32_t& o0, uint32_t& o1) {
  uint32_t ks2 = k0 ^ k1 ^ 0x1BD11BDAu;
  uint32_t x0 = c0 + k0, x1 = c1 + k1;
#define TFR(r) { x0 += x1; x1 = rotl32(x1, (r)); x1 ^= x0; }
  TFR(13) TFR(15) TFR(26) TFR(6)   x0 += k1;  x1 += ks2 + 1u;
  TFR(17) TFR(29) TFR(16) TFR(24)  x0 += ks2; x1 += k0 + 2u;
  TFR(13) TFR(15) TFR(26) TFR(6)   x0 += k0;  x1 += k1 + 3u;
  TFR(17) TFR(29) TFR(16) TFR(24)  x0 += k1;  x1 += ks2 + 4u;
  TFR(13) TFR(15) TFR(26) TFR(6)   x0 += ks2; x1 += k0 + 5u;
#undef TFR
  o0 = x0; o1 = x1;
}

// one 32-bit random word at flat position idx of a draw of `total` words
__device__ __forceinline__ uint32_t draw_bits(uint32_t k0, uint32_t k1,
                                              uint32_t idx, uint32_t total) {
  uint32_t o0, o1;
#if PARTITIONABLE
  (void)total;
  tf2x32(k0, k1, 0u, idx, o0, o1);
  return o0 ^ o1;
#else
  uint32_t hlf = total >> 1;
  if (idx < hlf) { tf2x32(k0, k1, idx, idx + hlf, o0, o1); return o0; }
  tf2x32(k0, k1, idx - hlf, idx, o0, o1); return o1;
#endif
}

// jax.random.uniform(tiny,1) -> gumbel, exact fp32 op sequence
__device__ __forceinline__ float bits_to_gumbel(uint32_t bits) {
  uint32_t fb = (bits >> 9) | 0x3F800000u;
  float f = __uint_as_float(fb) - 1.0f;            // [0,1)
  const float TINY = 1.17549435082228751e-38f;     // finfo(f32).tiny
  float u = f * (1.0f - TINY) + TINY;
  u = fmaxf(TINY, u);
  return -logf(-logf(u));
}

// XLA ElementalIrEmitter::EmitTanh rational approximation (f32):
// clamp to [-9,9], 7-term/4-term rational, passthrough for |x|<4e-4.
// contract(off): XLA emits unfused fmul/fadd chains.
__device__ __forceinline__ float xla_tanh(float x) {
#pragma clang fp contract(off)
  float ax = fabsf(x);
  float xc = fminf(fmaxf(x, -9.0f), 9.0f);
  float x2 = xc * xc;
  float nm = -2.76076847742355e-16f;
  nm = nm * x2 + 2.00018790482477e-13f;
  nm = nm * x2 + -8.60467152213735e-11f;
  nm = nm * x2 + 5.12229709037114e-08f;
  nm = nm * x2 + 1.48572235717979e-05f;
  nm = nm * x2 + 6.37261928875436e-04f;
  nm = nm * x2 + 4.89352455891786e-03f;
  nm = xc * nm;
  float dn = 1.19825839466702e-06f;
  dn = dn * x2 + 1.18534705686654e-04f;
  dn = dn * x2 + 2.26843463243900e-03f;
  dn = dn * x2 + 4.89352518554385e-03f;
  return (ax < 0.0004f) ? x : (nm / dn);
}

// dest[j] = (sum_k src[k]*W[k*128+j]) + pre[j] + bias[j]
// 256 threads: j = t&127, each half sums KLEN/2 elements; combine via LDS.
template<int KLEN>
__device__ __forceinline__ void matvec(const float* __restrict__ W,
                                       const float* __restrict__ src,
                                       const float* __restrict__ pre,
                                       const float* __restrict__ bias,
                                       float* dest, float* part, int t) {
  const int j  = t & 127;
  const int hv = t >> 7;
  const int kh = KLEN / 2;
  const int k0 = hv * kh;
  float acc = 0.f;
  const float* Wp = W + (size_t)k0 * EDIM + j;
  const float* sp = src + k0;
#pragma unroll 8
  for (int k = 0; k < kh; ++k) acc = fmaf(sp[k], Wp[(size_t)k * EDIM], acc);
  if (hv) part[j] = acc;
  __syncthreads();
  if (!hv) {
    float r = acc + part[j];
    if (pre)  r += pre[j];
    if (bias) r += bias[j];
    dest[j] = r;
  }
  __syncthreads();
}

// dst[n][j] = sum_k src[n][k]*W[k*128+j] + bias[j], for 2*RPH rows.
// thread t: j=t&127, rows (t>>7)+2s. NO internal sync (caller syncs).
template<int RPH>
__device__ __forceinline__ void computeK(const float* __restrict__ W,
                                         const float* __restrict__ bias,
                                         const float* src, float* dst, int t) {
  const int j  = t & 127;
  const int hv = t >> 7;
  float acc[RPH];
#pragma unroll
  for (int s = 0; s < RPH; ++s) acc[s] = 0.f;
  const float* Wp = W + j;
#pragma unroll 4
  for (int k = 0; k < EDIM; ++k) {
    float w = Wp[(size_t)k * EDIM];
#pragma unroll
    for (int s = 0; s < RPH; ++s)
      acc[s] = fmaf(src[(hv + 2 * s) * EDIM + k], w, acc[s]);
  }
  float bj = bias[j];
#pragma unroll
  for (int s = 0; s < RPH; ++s) dst[(hv + 2 * s) * EDIM + j] = acc[s] + bj;
}

__global__ __launch_bounds__(THREADS, 2)
void decoder_kernel(const float* __restrict__ node_context,
                    const float* __restrict__ cell_context,
                    const float* __restrict__ original_data,
                    const float* __restrict__ high_mask,
                    const float* __restrict__ low_mask,
                    const float* __restrict__ init_w,
                    const float* __restrict__ W_hc,  const float* __restrict__ b_hc,
                    const float* __restrict__ W_vw,  const float* __restrict__ b_vw,
                    const float* __restrict__ Wq,    const float* __restrict__ bq,
                    const float* __restrict__ Wk,    const float* __restrict__ bk,
                    const float* __restrict__ v_hi,
                    const float* __restrict__ low_init_w,
                    const float* __restrict__ low_W_hc, const float* __restrict__ low_b_hc,
                    const float* __restrict__ low_W_vw, const float* __restrict__ low_b_vw,
                    const float* __restrict__ low_Wq,   const float* __restrict__ low_bq,
                    const float* __restrict__ low_Wk,   const float* __restrict__ low_bk,
                    const float* __restrict__ v_lo,
                    float* __restrict__ out) {
  const int b = blockIdx.x;
  const int t = threadIdx.x;

  __shared__ float s_cc[NCELL][EDIM];
  __shared__ float s_Kh[NCELL][EDIM];
  __shared__ float s_emb[NNODE][EDIM];
  __shared__ float s_Kl[NNODE][EDIM];
  __shared__ float s_coords[NNODE][2];
  __shared__ float s_qh[EDIM], s_ql[EDIM], s_qq[EDIM];
  __shared__ float s_qbh[EDIM], s_qbl[EDIM];
  __shared__ float s_hbl[EDIM], s_hbh[EDIM];
  __shared__ float s_mean[EDIM], s_part[EDIM];
  __shared__ float s_vh[EDIM], s_vl[EDIM];
  __shared__ float s_iw[2 * EDIM], s_iwl[2 * EDIM];
  __shared__ float s_u[NNODE];
  __shared__ float s_maskl[NNODE];
  __shared__ float s_maskh[NCELL];
  __shared__ uint32_t s_kh[NCELL][2];   // high step keys
  __shared__ uint32_t s_kl[NCELL][2];   // per-cell low keys
  __shared__ uint32_t s_ks[NNODE][2];   // per-low-step keys (current cell)
  __shared__ uint32_t s_base[4];
#if !PARTITIONABLE
  __shared__ uint32_t s_tmp[4 * NCELL];
  __shared__ uint32_t s_ksp[2 * NNODE];
#endif
  __shared__ int s_idx;

  // ---------------- key derivation ----------------
  if (t == 0) {
    uint32_t a0, a1;
    tf2x32(0u, 42u, 0u, 0u, a0, a1); s_base[0] = a0; s_base[1] = a1;  // fold_in(root,0)
    tf2x32(0u, 42u, 0u, 1u, a0, a1); s_base[2] = a0; s_base[3] = a1;  // fold_in(root,1)
  }
  __syncthreads();
#if PARTITIONABLE
  if (t < NCELL) {
    tf2x32(s_base[0], s_base[1], 0u, (uint32_t)t, s_kh[t][0], s_kh[t][1]);
    tf2x32(s_base[2], s_base[3], 0u, (uint32_t)t, s_kl[t][0], s_kl[t][1]);
  }
#else
  if (t < NCELL) {
    uint32_t o0, o1;
    tf2x32(s_base[0], s_base[1], (uint32_t)t, (uint32_t)(t + NCELL), o0, o1);
    s_tmp[t] = o0; s_tmp[t + NCELL] = o1;
    tf2x32(s_base[2], s_base[3], (uint32_t)t, (uint32_t)(t + NCELL), o0, o1);
    s_tmp[2 * NCELL + t] = o0; s_tmp[3 * NCELL + t] = o1;
  }
  __syncthreads();
  if (t < NCELL) {
    s_kh[t][0] = s_tmp[2 * t];              s_kh[t][1] = s_tmp[2 * t + 1];
    s_kl[t][0] = s_tmp[2 * NCELL + 2 * t];  s_kl[t][1] = s_tmp[2 * NCELL + 2 * t + 1];
  }
#endif

  // ---------------- block-level setup ----------------
  if (t < EDIM) { s_vh[t] = v_hi[t]; s_vl[t] = v_lo[t]; }
  s_iw[t]  = init_w[t];        // t in [0,256)
  s_iwl[t] = low_init_w[t];
  if (t < NCELL) s_maskh[t] = high_mask[b * NCELL + t];

  if (t < EDIM) {
    float s = 0.f;
    for (int n = 0; n < NCELL; ++n) {
      float x = cell_context[((size_t)b * NCELL + n) * EDIM + t];
      s_cc[n][t] = x; s += x;
    }
    s_mean[t] = s / 12.0f;
  }
  __syncthreads();
  matvec<128>(W_hc, s_mean, nullptr, b_hc, s_hbh, s_part, t);       // h_bar high
  computeK<6>(Wk, bk, &s_cc[0][0], &s_Kh[0][0], t);                 // K_high
  __syncthreads();
  matvec<256>(W_vw, s_iw, s_hbh, b_vw, s_qh, s_part, t);            // q0 high
  if (t < EDIM) s_qbh[t] = s_hbh[t] + b_vw[t];
  __syncthreads();

  float cell_lp = 0.f, cell_rew = 0.f, lastx = 0.f, lasty = 0.f;    // wave0 regs

  for (int ci = 0; ci < NCELL; ++ci) {
    // ---- high attention scores
    matvec<128>(Wq, s_qh, nullptr, bq, s_qq, s_part, t);
    if (t < 4 * NCELL) {
      int nd = t >> 2, p = t & 3, rot = t & 31;
      float acc = 0.f;
#pragma unroll 4
      for (int i2 = 0; i2 < 32; ++i2) {
        int h = p * 32 + ((i2 + rot) & 31);
        acc = fmaf(s_vh[h], xla_tanh(s_qq[h] + s_Kh[nd][h]), acc);
      }
      acc += __shfl_xor(acc, 1);
      acc += __shfl_xor(acc, 2);
      if (p == 0) s_u[nd] = acc;
    }
    __syncthreads();

    // ---- sample high cell (wave 0)
    if (t < 64) {
      float logit = -__builtin_huge_valf(), val = -__builtin_huge_valf();
      if (t < NCELL) {
        float lg = (s_maskh[t] > 0.f) ? -1e9f : 10.0f * xla_tanh(s_u[t]);
        logit = lg;
        uint32_t bits = draw_bits(s_kh[ci][0], s_kh[ci][1],
                                  (uint32_t)(b * NCELL + t), (uint32_t)(NB * NCELL));
        val = lg + bits_to_gumbel(bits);
      }
      int bidx = t;
#pragma unroll
      for (int d = 32; d; d >>= 1) {
        float oval = __shfl_xor(val, d);
        int   oidx = __shfl_xor(bidx, d);
        if (oval > val || (oval == val && oidx < bidx)) { val = oval; bidx = oidx; }
      }
      float mx = logit;
#pragma unroll
      for (int d = 32; d; d >>= 1) mx = fmaxf(mx, __shfl_xor(mx, d));
      float ex = (t < NCELL) ? expf(logit - mx) : 0.f;
#pragma unroll
      for (int d = 32; d; d >>= 1) ex += __shfl_xor(ex, d);
      float chosen = __shfl(logit, bidx);
      cell_lp += (chosen - mx) - logf(ex);
      if (t == 0) {
        s_idx = bidx;
        s_maskh[bidx] = 1.0f;
        out[OFF_CACT + b * NCELL + ci] = (float)bidx;
      }
    }
    __syncthreads();
    const int cidx = s_idx;

    // ---- next high query (uses selected cell embedding)
    if (ci == 0)
      matvec<128>(W_vw, &s_cc[cidx][0], s_qbh, nullptr, s_qbh, s_part, t);         // + init_h @ W_vw_top
    if (ci < NCELL - 1)
      matvec<128>(W_vw + 128 * EDIM, &s_cc[cidx][0], s_qbh, nullptr, s_qh, s_part, t);

    // ---- stage selected cell: emb, coords, low mask, mean
    const float* embg = node_context + (((size_t)b * NCELL + cidx) * NNODE) * EDIM;
    if (t < EDIM) {
      float s = 0.f;
      for (int n = 0; n < NNODE; ++n) {
        float x = embg[n * EDIM + t];
        s_emb[n][t] = x; s += x;
      }
      s_mean[t] = s / 40.0f;
    }
    if (t >= 128 && t < 208) {
      int q = t - 128;
      s_coords[q >> 1][q & 1] = original_data[(((size_t)b * NCELL + cidx) * NNODE) * 2 + q];
    }
    if (t >= 208 && t < 208 + NNODE) s_maskl[t - 208] = low_mask[b * NNODE + (t - 208)];
    __syncthreads();
    matvec<128>(low_W_hc, s_mean, nullptr, low_b_hc, s_hbl, s_part, t);   // h_bar low
    computeK<20>(low_Wk, low_bk, &s_emb[0][0], &s_Kl[0][0], t);           // K_low
#if PARTITIONABLE
    if (t < NNODE) tf2x32(s_kl[ci][0], s_kl[ci][1], 0u, (uint32_t)t, s_ks[t][0], s_ks[t][1]);
#else
    if (t < NNODE) {
      uint32_t o0, o1;
      tf2x32(s_kl[ci][0], s_kl[ci][1], (uint32_t)t, (uint32_t)(t + NNODE), o0, o1);
      s_ksp[t] = o0; s_ksp[t + NNODE] = o1;
    }
#endif
    __syncthreads();
#if !PARTITIONABLE
    if (t < NNODE) { s_ks[t][0] = s_ksp[2 * t]; s_ks[t][1] = s_ksp[2 * t + 1]; }
#endif
    matvec<256>(low_W_vw, s_iwl, s_hbl, low_b_vw, s_ql, s_part, t);       // q0 low
    if (t < EDIM) s_qbl[t] = s_hbl[t] + low_b_vw[t];
    __syncthreads();

    // ---------------- low decode: 40 steps ----------------
    float llp = 0.f, rew = 0.f, prevx = 0.f, prevy = 0.f, initx = 0.f, inity = 0.f;
    for (int st = 0; st < NNODE; ++st) {
      matvec<128>(low_Wq, s_ql, nullptr, low_bq, s_qq, s_part, t);
      if (t < 160) {
        int nd = t >> 2, p = t & 3, rot = t & 31;
        float acc = 0.f;
#pragma unroll 4
        for (int i2 = 0; i2 < 32; ++i2) {
          int h = p * 32 + ((i2 + rot) & 31);
          acc = fmaf(s_vl[h], xla_tanh(s_qq[h] + s_Kl[nd][h]), acc);
        }
        acc += __shfl_xor(acc, 1);
        acc += __shfl_xor(acc, 2);
        if (p == 0) s_u[nd] = acc;
      }
      __syncthreads();

      if (t < 64) {
        float logit = -__builtin_huge_valf(), val = -__builtin_huge_valf();
        if (t < NNODE) {
          float lg = (s_maskl[t] > 0.f) ? -1e9f : 10.0f * xla_tanh(s_u[t]);
          logit = lg;
          uint32_t bits = draw_bits(s_ks[st][0], s_ks[st][1],
                                    (uint32_t)(b * NNODE + t), (uint32_t)(NB * NNODE));
          val = lg + bits_to_gumbel(bits);
        }
        int bidx = t;
#pragma unroll
        for (int d = 32; d; d >>= 1) {
          float oval = __shfl_xor(val, d);
          int   oidx = __shfl_xor(bidx, d);
          if (oval > val || (oval == val && oidx < bidx)) { val = oval; bidx = oidx; }
        }
        float mx = logit;
#pragma unroll
        for (int d = 32; d; d >>= 1) mx = fmaxf(mx, __shfl_xor(mx, d));
        float ex = (t < NNODE) ? expf(logit - mx) : 0.f;
#pragma unroll
        for (int d = 32; d; d >>= 1) ex += __shfl_xor(ex, d);
        float chosen = __shfl(logit, bidx);
        llp += (chosen - mx) - logf(ex);
        float cx = s_coords[bidx][0], cy = s_coords[bidx][1];
        if (st == 0) { initx = cx; inity = cy; }
        else { float dx = cx - prevx, dy = cy - prevy; rew += sqrtf(dx * dx + dy * dy); }
        prevx = cx; prevy = cy;
        if (t == 0) {
          s_idx = bidx;
          s_maskl[bidx] = 1.0f;
          out[OFF_NACT + ((size_t)(b * NCELL + ci)) * NNODE + st] = (float)bidx;
        }
      }
      __syncthreads();
      const int ni = s_idx;
      if (st == 0)
        matvec<128>(low_W_vw, &s_emb[ni][0], s_qbl, nullptr, s_qbl, s_part, t);     // + init_h @ W_vw_top
      if (st < NNODE - 1)
        matvec<128>(low_W_vw + 128 * EDIM, &s_emb[ni][0], s_qbl, nullptr, s_ql, s_part, t);
    }

    // ---- finish cell (wave0 registers only)
    if (t < 64) {
      if (ci > 0) {
        float dx = initx - lastx, dy = inity - lasty;
        cell_rew += sqrtf(dx * dx + dy * dy);
      }
      lastx = prevx; lasty = prevy;
      if (t == 0) {
        out[OFF_NLP + b * NCELL + ci] = llp;
        out[OFF_NRW + b * NCELL + ci] = rew;
      }
    }
  }

  if (t == 0) {
    out[OFF_CLP + b] = cell_lp;
    out[OFF_CRW + b] = cell_rew;
  }
}

extern "C" void kernel_launch(void* const* d_in, const int* in_sizes, int n_in,
                              void* d_out, int out_size, void* d_ws, size_t ws_size,
                              hipStream_t stream) {
  (void)in_sizes; (void)n_in; (void)out_size; (void)d_ws; (void)ws_size;
  decoder_kernel<<<NB, THREADS, 0, stream>>>(
      (const float*)d_in[0],  (const float*)d_in[1],  (const float*)d_in[2],
      (const float*)d_in[3],  (const float*)d_in[4],  (const float*)d_in[5],
      (const float*)d_in[6],  (const float*)d_in[7],  (const float*)d_in[8],
      (const float*)d_in[9],  (const float*)d_in[10], (const float*)d_in[11],
      (const float*)d_in[12], (const float*)d_in[13], (const float*)d_in[14],
      (const float*)d_in[15], (const float*)d_in[16], (const float*)d_in[17],
      (const float*)d_in[18], (const float*)d_in[19], (const float*)d_in[20],
      (const float*)d_in[21], (const float*)d_in[22], (const float*)d_in[23],
      (const float*)d_in[24],
      (float*)d_out);
}

// Round 2
// 3869.167 us; speedup vs baseline: 1.1813x; 1.1813x over previous
//
#include <hip/hip_runtime.h>
#include <stdint.h>

// ---------------------------------------------------------------------------
// Decoder_72516227826046: hierarchical pointer-net decoder, bit-faithful JAX
// threefry PRNG + gumbel-max categorical, fp32 throughout.
// One block per batch element (512 blocks x 256 threads).
// R2: register-cache the two per-step 64KB weight matrices (low_Wq and the
// bottom half of low_W_vw). Thread t (j=t&127, half hv=t>>7) holds
// W[hv*64+k][j], k=0..63 in VGPRs -> per-step matvecs are 64 reg-FMAs with
// LDS float4 query reads, no global traffic. FMA order is bit-identical to
// the round-1 passing kernel (ascending k within each 64-half, same combine
// order), so sampling trajectories are unchanged.
// ---------------------------------------------------------------------------

#define PARTITIONABLE 1

#define NB    512
#define NCELL 12
#define NNODE 40
#define EDIM  128
#define THREADS 256

// output layout (all float32)
#define OFF_CLP  0                    // cell_log_prob [512]
#define OFF_NLP  512                  // node_log_prob [6144]
#define OFF_CRW  6656                 // cell_reward   [512]
#define OFF_NRW  7168                 // node_reward   [6144]
#define OFF_CACT 13312                // cell_action   [6144]
#define OFF_NACT 19456                // node_action   [245760]

// ---------------- threefry2x32 (bit-exact vs jax._src.prng) ----------------
__device__ __forceinline__ uint32_t rotl32(uint32_t x, int d) {
  return (x << d) | (x >> (32 - d));
}

__device__ __forceinline__ void tf2x32(uint32_t k0, uint32_t k1,
                                       uint32_t c0, uint32_t c1,
                                       uint32_t& o0, uint32_t& o1) {
  uint32_t ks2 = k0 ^ k1 ^ 0x1BD11BDAu;
  uint32_t x0 = c0 + k0, x1 = c1 + k1;
#define TFR(r) { x0 += x1; x1 = rotl32(x1, (r)); x1 ^= x0; }
  TFR(13) TFR(15) TFR(26) TFR(6)   x0 += k1;  x1 += ks2 + 1u;
  TFR(17) TFR(29) TFR(16) TFR(24)  x0 += ks2; x1 += k0 + 2u;
  TFR(13) TFR(15) TFR(26) TFR(6)   x0 += k0;  x1 += k1 + 3u;
  TFR(17) TFR(29) TFR(16) TFR(24)  x0 += k1;  x1 += ks2 + 4u;
  TFR(13) TFR(15) TFR(26) TFR(6)   x0 += ks2; x1 += k0 + 5u;
#undef TFR
  o0 = x0; o1 = x1;
}

__device__ __forceinline__ uint32_t draw_bits(uint32_t k0, uint32_t k1,
                                              uint32_t idx, uint32_t total) {
  uint32_t o0, o1;
#if PARTITIONABLE
  (void)total;
  tf2x32(k0, k1, 0u, idx, o0, o1);
  return o0 ^ o1;
#else
  uint32_t hlf = total >> 1;
  if (idx < hlf) { tf2x32(k0, k1, idx, idx + hlf, o0, o1); return o0; }
  tf2x32(k0, k1, idx - hlf, idx, o0, o1); return o1;
#endif
}

__device__ __forceinline__ float bits_to_gumbel(uint32_t bits) {
  uint32_t fb = (bits >> 9) | 0x3F800000u;
  float f = __uint_as_float(fb) - 1.0f;            // [0,1)
  const float TINY = 1.17549435082228751e-38f;
  float u = f * (1.0f - TINY) + TINY;
  u = fmaxf(TINY, u);
  return -logf(-logf(u));
}

__device__ __forceinline__ float xla_tanh(float x) {
#pragma clang fp contract(off)
  float ax = fabsf(x);
  float xc = fminf(fmaxf(x, -9.0f), 9.0f);
  float x2 = xc * xc;
  float nm = -2.76076847742355e-16f;
  nm = nm * x2 + 2.00018790482477e-13f;
  nm = nm * x2 + -8.60467152213735e-11f;
  nm = nm * x2 + 5.12229709037114e-08f;
  nm = nm * x2 + 1.48572235717979e-05f;
  nm = nm * x2 + 6.37261928875436e-04f;
  nm = nm * x2 + 4.89352455891786e-03f;
  nm = xc * nm;
  float dn = 1.19825839466702e-06f;
  dn = dn * x2 + 1.18534705686654e-04f;
  dn = dn * x2 + 2.26843463243900e-03f;
  dn = dn * x2 + 4.89352518554385e-03f;
  return (ax < 0.0004f) ? x : (nm / dn);
}

// pointer-based matvec (setup/high-level path, unchanged from round 1)
template<int KLEN>
__device__ __forceinline__ void matvec(const float* __restrict__ W,
                                       const float* __restrict__ src,
                                       const float* __restrict__ pre,
                                       const float* __restrict__ bias,
                                       float* dest, float* part, int t) {
  const int j  = t & 127;
  const int hv = t >> 7;
  const int kh = KLEN / 2;
  const int k0 = hv * kh;
  float acc = 0.f;
  const float* Wp = W + (size_t)k0 * EDIM + j;
  const float* sp = src + k0;
#pragma unroll 8
  for (int k = 0; k < kh; ++k) acc = fmaf(sp[k], Wp[(size_t)k * EDIM], acc);
  if (hv) part[j] = acc;
  __syncthreads();
  if (!hv) {
    float r = acc + part[j];
    if (pre)  r += pre[j];
    if (bias) r += bias[j];
    dest[j] = r;
  }
  __syncthreads();
}

// register-weight matvec: rw[k] = W[k0+k][j] held in VGPRs.
// Identical FMA sequence to matvec<128> (ascending k, same combine order).
__device__ __forceinline__ void matvec_reg(const float rw[64],
                                           const float* __restrict__ src,
                                           const float* __restrict__ pre,
                                           const float* __restrict__ bias,
                                           float* dest, float* part,
                                           int j, int hv) {
  const float* sp = src + hv * 64;
  float acc = 0.f;
#pragma unroll
  for (int k = 0; k < 64; k += 4) {
    float4 s4 = *reinterpret_cast<const float4*>(sp + k);
    acc = fmaf(s4.x, rw[k + 0], acc);
    acc = fmaf(s4.y, rw[k + 1], acc);
    acc = fmaf(s4.z, rw[k + 2], acc);
    acc = fmaf(s4.w, rw[k + 3], acc);
  }
  if (hv) part[j] = acc;
  __syncthreads();
  if (!hv) {
    float r = acc + part[j];
    if (pre)  r += pre[j];
    if (bias) r += bias[j];
    dest[j] = r;
  }
  __syncthreads();
}

template<int RPH>
__device__ __forceinline__ void computeK(const float* __restrict__ W,
                                         const float* __restrict__ bias,
                                         const float* src, float* dst, int t) {
  const int j  = t & 127;
  const int hv = t >> 7;
  float acc[RPH];
#pragma unroll
  for (int s = 0; s < RPH; ++s) acc[s] = 0.f;
  const float* Wp = W + j;
#pragma unroll 4
  for (int k = 0; k < EDIM; ++k) {
    float w = Wp[(size_t)k * EDIM];
#pragma unroll
    for (int s = 0; s < RPH; ++s)
      acc[s] = fmaf(src[(hv + 2 * s) * EDIM + k], w, acc[s]);
  }
  float bj = bias[j];
#pragma unroll
  for (int s = 0; s < RPH; ++s) dst[(hv + 2 * s) * EDIM + j] = acc[s] + bj;
}

__global__ __launch_bounds__(THREADS, 2)
void decoder_kernel(const float* __restrict__ node_context,
                    const float* __restrict__ cell_context,
                    const float* __restrict__ original_data,
                    const float* __restrict__ high_mask,
                    const float* __restrict__ low_mask,
                    const float* __restrict__ init_w,
                    const float* __restrict__ W_hc,  const float* __restrict__ b_hc,
                    const float* __restrict__ W_vw,  const float* __restrict__ b_vw,
                    const float* __restrict__ Wq,    const float* __restrict__ bq,
                    const float* __restrict__ Wk,    const float* __restrict__ bk,
                    const float* __restrict__ v_hi,
                    const float* __restrict__ low_init_w,
                    const float* __restrict__ low_W_hc, const float* __restrict__ low_b_hc,
                    const float* __restrict__ low_W_vw, const float* __restrict__ low_b_vw,
                    const float* __restrict__ low_Wq,   const float* __restrict__ low_bq,
                    const float* __restrict__ low_Wk,   const float* __restrict__ low_bk,
                    const float* __restrict__ v_lo,
                    float* __restrict__ out) {
  const int b = blockIdx.x;
  const int t = threadIdx.x;
  const int j  = t & 127;
  const int hv = t >> 7;

  __shared__ float s_cc[NCELL][EDIM];
  __shared__ float s_Kh[NCELL][EDIM];
  __shared__ float s_emb[NNODE][EDIM];
  __shared__ float s_Kl[NNODE][EDIM];
  __shared__ float s_coords[NNODE][2];
  __shared__ float s_qh[EDIM], s_ql[EDIM], s_qq[EDIM];
  __shared__ float s_qbh[EDIM], s_qbl[EDIM];
  __shared__ float s_hbl[EDIM], s_hbh[EDIM];
  __shared__ float s_mean[EDIM], s_part[EDIM];
  __shared__ float s_vh[EDIM], s_vl[EDIM];
  __shared__ float s_bqh[EDIM], s_bql[EDIM];     // bq / low_bq staged in LDS
  __shared__ float s_iw[2 * EDIM], s_iwl[2 * EDIM];
  __shared__ float s_u[NNODE];
  __shared__ float s_maskl[NNODE];
  __shared__ float s_maskh[NCELL];
  __shared__ uint32_t s_kh[NCELL][2];
  __shared__ uint32_t s_kl[NCELL][2];
  __shared__ uint32_t s_ks[NNODE][2];
  __shared__ uint32_t s_base[4];
#if !PARTITIONABLE
  __shared__ uint32_t s_tmp[4 * NCELL];
  __shared__ uint32_t s_ksp[2 * NNODE];
#endif
  __shared__ int s_idx;

  // ---- register-cache the two per-step weight matrices (64 VGPR each) ----
  float rwq[64];   // low_Wq[hv*64+k][j]
  float rwv[64];   // low_W_vw[128 + hv*64 + k][j]  (bottom half)
  {
    const float* gq = low_Wq + (size_t)(hv * 64) * EDIM + j;
    const float* gv = low_W_vw + (size_t)(128 + hv * 64) * EDIM + j;
#pragma unroll
    for (int k = 0; k < 64; ++k) rwq[k] = gq[(size_t)k * EDIM];
#pragma unroll
    for (int k = 0; k < 64; ++k) rwv[k] = gv[(size_t)k * EDIM];
  }

  // ---------------- key derivation ----------------
  if (t == 0) {
    uint32_t a0, a1;
    tf2x32(0u, 42u, 0u, 0u, a0, a1); s_base[0] = a0; s_base[1] = a1;
    tf2x32(0u, 42u, 0u, 1u, a0, a1); s_base[2] = a0; s_base[3] = a1;
  }
  __syncthreads();
#if PARTITIONABLE
  if (t < NCELL) {
    tf2x32(s_base[0], s_base[1], 0u, (uint32_t)t, s_kh[t][0], s_kh[t][1]);
    tf2x32(s_base[2], s_base[3], 0u, (uint32_t)t, s_kl[t][0], s_kl[t][1]);
  }
#else
  if (t < NCELL) {
    uint32_t o0, o1;
    tf2x32(s_base[0], s_base[1], (uint32_t)t, (uint32_t)(t + NCELL), o0, o1);
    s_tmp[t] = o0; s_tmp[t + NCELL] = o1;
    tf2x32(s_base[2], s_base[3], (uint32_t)t, (uint32_t)(t + NCELL), o0, o1);
    s_tmp[2 * NCELL + t] = o0; s_tmp[3 * NCELL + t] = o1;
  }
  __syncthreads();
  if (t < NCELL) {
    s_kh[t][0] = s_tmp[2 * t];              s_kh[t][1] = s_tmp[2 * t + 1];
    s_kl[t][0] = s_tmp[2 * NCELL + 2 * t];  s_kl[t][1] = s_tmp[2 * NCELL + 2 * t + 1];
  }
#endif

  // ---------------- block-level setup ----------------
  if (t < EDIM) {
    s_vh[t] = v_hi[t]; s_vl[t] = v_lo[t];
    s_bqh[t] = bq[t];  s_bql[t] = low_bq[t];
  }
  s_iw[t]  = init_w[t];
  s_iwl[t] = low_init_w[t];
  if (t < NCELL) s_maskh[t] = high_mask[b * NCELL + t];

  if (t < EDIM) {
    float s = 0.f;
    for (int n = 0; n < NCELL; ++n) {
      float x = cell_context[((size_t)b * NCELL + n) * EDIM + t];
      s_cc[n][t] = x; s += x;
    }
    s_mean[t] = s / 12.0f;
  }
  __syncthreads();
  matvec<128>(W_hc, s_mean, nullptr, b_hc, s_hbh, s_part, t);
  computeK<6>(Wk, bk, &s_cc[0][0], &s_Kh[0][0], t);
  __syncthreads();
  matvec<256>(W_vw, s_iw, s_hbh, b_vw, s_qh, s_part, t);
  if (t < EDIM) s_qbh[t] = s_hbh[t] + b_vw[t];
  __syncthreads();

  float cell_lp = 0.f, cell_rew = 0.f, lastx = 0.f, lasty = 0.f;

  for (int ci = 0; ci < NCELL; ++ci) {
    // ---- high attention scores
    matvec<128>(Wq, s_qh, nullptr, s_bqh, s_qq, s_part, t);
    if (t < 4 * NCELL) {
      int nd = t >> 2, p = t & 3, rot = t & 31;
      float acc = 0.f;
#pragma unroll 4
      for (int i2 = 0; i2 < 32; ++i2) {
        int h = p * 32 + ((i2 + rot) & 31);
        acc = fmaf(s_vh[h], xla_tanh(s_qq[h] + s_Kh[nd][h]), acc);
      }
      acc += __shfl_xor(acc, 1);
      acc += __shfl_xor(acc, 2);
      if (p == 0) s_u[nd] = acc;
    }
    __syncthreads();

    // ---- sample high cell (wave 0)
    if (t < 64) {
      float logit = -__builtin_huge_valf(), val = -__builtin_huge_valf();
      if (t < NCELL) {
        float lg = (s_maskh[t] > 0.f) ? -1e9f : 10.0f * xla_tanh(s_u[t]);
        logit = lg;
        uint32_t bits = draw_bits(s_kh[ci][0], s_kh[ci][1],
                                  (uint32_t)(b * NCELL + t), (uint32_t)(NB * NCELL));
        val = lg + bits_to_gumbel(bits);
      }
      int bidx = t;
#pragma unroll
      for (int d = 32; d; d >>= 1) {
        float oval = __shfl_xor(val, d);
        int   oidx = __shfl_xor(bidx, d);
        if (oval > val || (oval == val && oidx < bidx)) { val = oval; bidx = oidx; }
      }
      float mx = logit;
#pragma unroll
      for (int d = 32; d; d >>= 1) mx = fmaxf(mx, __shfl_xor(mx, d));
      float ex = (t < NCELL) ? expf(logit - mx) : 0.f;
#pragma unroll
      for (int d = 32; d; d >>= 1) ex += __shfl_xor(ex, d);
      float chosen = __shfl(logit, bidx);
      cell_lp += (chosen - mx) - logf(ex);
      if (t == 0) {
        s_idx = bidx;
        s_maskh[bidx] = 1.0f;
        out[OFF_CACT + b * NCELL + ci] = (float)bidx;
      }
    }
    __syncthreads();
    const int cidx = s_idx;

    // ---- next high query
    if (ci == 0)
      matvec<128>(W_vw, &s_cc[cidx][0], s_qbh, nullptr, s_qbh, s_part, t);
    if (ci < NCELL - 1)
      matvec<128>(W_vw + 128 * EDIM, &s_cc[cidx][0], s_qbh, nullptr, s_qh, s_part, t);

    // ---- stage selected cell
    const float* embg = node_context + (((size_t)b * NCELL + cidx) * NNODE) * EDIM;
    if (t < EDIM) {
      float s = 0.f;
      for (int n = 0; n < NNODE; ++n) {
        float x = embg[n * EDIM + t];
        s_emb[n][t] = x; s += x;
      }
      s_mean[t] = s / 40.0f;
    }
    if (t >= 128 && t < 208) {
      int q = t - 128;
      s_coords[q >> 1][q & 1] = original_data[(((size_t)b * NCELL + cidx) * NNODE) * 2 + q];
    }
    if (t >= 208 && t < 208 + NNODE) s_maskl[t - 208] = low_mask[b * NNODE + (t - 208)];
    __syncthreads();
    matvec<128>(low_W_hc, s_mean, nullptr, low_b_hc, s_hbl, s_part, t);
    computeK<20>(low_Wk, low_bk, &s_emb[0][0], &s_Kl[0][0], t);
#if PARTITIONABLE
    if (t < NNODE) tf2x32(s_kl[ci][0], s_kl[ci][1], 0u, (uint32_t)t, s_ks[t][0], s_ks[t][1]);
#else
    if (t < NNODE) {
      uint32_t o0, o1;
      tf2x32(s_kl[ci][0], s_kl[ci][1], (uint32_t)t, (uint32_t)(t + NNODE), o0, o1);
      s_ksp[t] = o0; s_ksp[t + NNODE] = o1;
    }
#endif
    __syncthreads();
#if !PARTITIONABLE
    if (t < NNODE) { s_ks[t][0] = s_ksp[2 * t]; s_ks[t][1] = s_ksp[2 * t + 1]; }
#endif
    matvec<256>(low_W_vw, s_iwl, s_hbl, low_b_vw, s_ql, s_part, t);
    if (t < EDIM) s_qbl[t] = s_hbl[t] + low_b_vw[t];
    __syncthreads();

    // ---------------- low decode: 40 steps ----------------
    float llp = 0.f, rew = 0.f, prevx = 0.f, prevy = 0.f, initx = 0.f, inity = 0.f;
    for (int st = 0; st < NNODE; ++st) {
      matvec_reg(rwq, s_ql, nullptr, s_bql, s_qq, s_part, j, hv);
      if (t < 160) {
        int nd = t >> 2, p = t & 3, rot = t & 31;
        float acc = 0.f;
#pragma unroll 4
        for (int i2 = 0; i2 < 32; ++i2) {
          int h = p * 32 + ((i2 + rot) & 31);
          acc = fmaf(s_vl[h], xla_tanh(s_qq[h] + s_Kl[nd][h]), acc);
        }
        acc += __shfl_xor(acc, 1);
        acc += __shfl_xor(acc, 2);
        if (p == 0) s_u[nd] = acc;
      }
      __syncthreads();

      if (t < 64) {
        float logit = -__builtin_huge_valf(), val = -__builtin_huge_valf();
        if (t < NNODE) {
          float lg = (s_maskl[t] > 0.f) ? -1e9f : 10.0f * xla_tanh(s_u[t]);
          logit = lg;
          uint32_t bits = draw_bits(s_ks[st][0], s_ks[st][1],
                                    (uint32_t)(b * NNODE + t), (uint32_t)(NB * NNODE));
          val = lg + bits_to_gumbel(bits);
        }
        int bidx = t;
#pragma unroll
        for (int d = 32; d; d >>= 1) {
          float oval = __shfl_xor(val, d);
          int   oidx = __shfl_xor(bidx, d);
          if (oval > val || (oval == val && oidx < bidx)) { val = oval; bidx = oidx; }
        }
        float mx = logit;
#pragma unroll
        for (int d = 32; d; d >>= 1) mx = fmaxf(mx, __shfl_xor(mx, d));
        float ex = (t < NNODE) ? expf(logit - mx) : 0.f;
#pragma unroll
        for (int d = 32; d; d >>= 1) ex += __shfl_xor(ex, d);
        float chosen = __shfl(logit, bidx);
        llp += (chosen - mx) - logf(ex);
        float cx = s_coords[bidx][0], cy = s_coords[bidx][1];
        if (st == 0) { initx = cx; inity = cy; }
        else { float dx = cx - prevx, dy = cy - prevy; rew += sqrtf(dx * dx + dy * dy); }
        prevx = cx; prevy = cy;
        if (t == 0) {
          s_idx = bidx;
          s_maskl[bidx] = 1.0f;
          out[OFF_NACT + ((size_t)(b * NCELL + ci)) * NNODE + st] = (float)bidx;
        }
      }
      __syncthreads();
      const int ni = s_idx;
      if (st == 0)
        matvec<128>(low_W_vw, &s_emb[ni][0], s_qbl, nullptr, s_qbl, s_part, t);
      if (st < NNODE - 1)
        matvec_reg(rwv, &s_emb[ni][0], s_qbl, nullptr, s_ql, s_part, j, hv);
    }

    // ---- finish cell
    if (t < 64) {
      if (ci > 0) {
        float dx = initx - lastx, dy = inity - lasty;
        cell_rew += sqrtf(dx * dx + dy * dy);
      }
      lastx = prevx; lasty = prevy;
      if (t == 0) {
        out[OFF_NLP + b * NCELL + ci] = llp;
        out[OFF_NRW + b * NCELL + ci] = rew;
      }
    }
  }

  if (t == 0) {
    out[OFF_CLP + b] = cell_lp;
    out[OFF_CRW + b] = cell_rew;
  }
}

extern "C" void kernel_launch(void* const* d_in, const int* in_sizes, int n_in,
                              void* d_out, int out_size, void* d_ws, size_t ws_size,
                              hipStream_t stream) {
  (void)in_sizes; (void)n_in; (void)out_size; (void)d_ws; (void)ws_size;
  decoder_kernel<<<NB, THREADS, 0, stream>>>(
      (const float*)d_in[0],  (const float*)d_in[1],  (const float*)d_in[2],
      (const float*)d_in[3],  (const float*)d_in[4],  (const float*)d_in[5],
      (const float*)d_in[6],  (const float*)d_in[7],  (const float*)d_in[8],
      (const float*)d_in[9],  (const float*)d_in[10], (const float*)d_in[11],
      (const float*)d_in[12], (const float*)d_in[13], (const float*)d_in[14],
      (const float*)d_in[15], (const float*)d_in[16], (const float*)d_in[17],
      (const float*)d_in[18], (const float*)d_in[19], (const float*)d_in[20],
      (const float*)d_in[21], (const float*)d_in[22], (const float*)d_in[23],
      (const float*)d_in[24],
      (float*)d_out);
}

// Round 3
// 3811.389 us; speedup vs baseline: 1.1992x; 1.0152x over previous
//
#include <hip/hip_runtime.h>
#include <stdint.h>

// ---------------------------------------------------------------------------
// Decoder_72516227826046: hierarchical pointer-net decoder, bit-faithful JAX
// threefry PRNG + gumbel-max categorical, fp32 throughout.
// One block per batch element (512 blocks x 256 threads).
// R3: register-cache low_Wq and low_W_vw(bottom) for real this time. R2's
// array-parameter version decayed to a pointer -> scratch spill (WRITE_SIZE
// 33MB, VGPR stuck at 128). The register matvec is now a macro so rwq/rwv
// are only accessed with compile-time-constant indices -> SROA promotes to
// VGPRs. FMA order is bit-identical to the passing round-1 kernel.
// ---------------------------------------------------------------------------

#define PARTITIONABLE 1

#define NB    512
#define NCELL 12
#define NNODE 40
#define EDIM  128
#define THREADS 256

// output layout (all float32)
#define OFF_CLP  0                    // cell_log_prob [512]
#define OFF_NLP  512                  // node_log_prob [6144]
#define OFF_CRW  6656                 // cell_reward   [512]
#define OFF_NRW  7168                 // node_reward   [6144]
#define OFF_CACT 13312                // cell_action   [6144]
#define OFF_NACT 19456                // node_action   [245760]

// ---------------- threefry2x32 (bit-exact vs jax._src.prng) ----------------
__device__ __forceinline__ uint32_t rotl32(uint32_t x, int d) {
  return (x << d) | (x >> (32 - d));
}

__device__ __forceinline__ void tf2x32(uint32_t k0, uint32_t k1,
                                       uint32_t c0, uint32_t c1,
                                       uint32_t& o0, uint32_t& o1) {
  uint32_t ks2 = k0 ^ k1 ^ 0x1BD11BDAu;
  uint32_t x0 = c0 + k0, x1 = c1 + k1;
#define TFR(r) { x0 += x1; x1 = rotl32(x1, (r)); x1 ^= x0; }
  TFR(13) TFR(15) TFR(26) TFR(6)   x0 += k1;  x1 += ks2 + 1u;
  TFR(17) TFR(29) TFR(16) TFR(24)  x0 += ks2; x1 += k0 + 2u;
  TFR(13) TFR(15) TFR(26) TFR(6)   x0 += k0;  x1 += k1 + 3u;
  TFR(17) TFR(29) TFR(16) TFR(24)  x0 += k1;  x1 += ks2 + 4u;
  TFR(13) TFR(15) TFR(26) TFR(6)   x0 += ks2; x1 += k0 + 5u;
#undef TFR
  o0 = x0; o1 = x1;
}

__device__ __forceinline__ uint32_t draw_bits(uint32_t k0, uint32_t k1,
                                              uint32_t idx, uint32_t total) {
  uint32_t o0, o1;
#if PARTITIONABLE
  (void)total;
  tf2x32(k0, k1, 0u, idx, o0, o1);
  return o0 ^ o1;
#else
  uint32_t hlf = total >> 1;
  if (idx < hlf) { tf2x32(k0, k1, idx, idx + hlf, o0, o1); return o0; }
  tf2x32(k0, k1, idx - hlf, idx, o0, o1); return o1;
#endif
}

__device__ __forceinline__ float bits_to_gumbel(uint32_t bits) {
  uint32_t fb = (bits >> 9) | 0x3F800000u;
  float f = __uint_as_float(fb) - 1.0f;            // [0,1)
  const float TINY = 1.17549435082228751e-38f;
  float u = f * (1.0f - TINY) + TINY;
  u = fmaxf(TINY, u);
  return -logf(-logf(u));
}

__device__ __forceinline__ float xla_tanh(float x) {
#pragma clang fp contract(off)
  float ax = fabsf(x);
  float xc = fminf(fmaxf(x, -9.0f), 9.0f);
  float x2 = xc * xc;
  float nm = -2.76076847742355e-16f;
  nm = nm * x2 + 2.00018790482477e-13f;
  nm = nm * x2 + -8.60467152213735e-11f;
  nm = nm * x2 + 5.12229709037114e-08f;
  nm = nm * x2 + 1.48572235717979e-05f;
  nm = nm * x2 + 6.37261928875436e-04f;
  nm = nm * x2 + 4.89352455891786e-03f;
  nm = xc * nm;
  float dn = 1.19825839466702e-06f;
  dn = dn * x2 + 1.18534705686654e-04f;
  dn = dn * x2 + 2.26843463243900e-03f;
  dn = dn * x2 + 4.89352518554385e-03f;
  return (ax < 0.0004f) ? x : (nm / dn);
}

// pointer-based matvec (setup/high-level path)
template<int KLEN>
__device__ __forceinline__ void matvec(const float* __restrict__ W,
                                       const float* __restrict__ src,
                                       const float* __restrict__ pre,
                                       const float* __restrict__ bias,
                                       float* dest, float* part, int t) {
  const int j  = t & 127;
  const int hv = t >> 7;
  const int kh = KLEN / 2;
  const int k0 = hv * kh;
  float acc = 0.f;
  const float* Wp = W + (size_t)k0 * EDIM + j;
  const float* sp = src + k0;
#pragma unroll 8
  for (int k = 0; k < kh; ++k) acc = fmaf(sp[k], Wp[(size_t)k * EDIM], acc);
  if (hv) part[j] = acc;
  __syncthreads();
  if (!hv) {
    float r = acc + part[j];
    if (pre)  r += pre[j];
    if (bias) r += bias[j];
    dest[j] = r;
  }
  __syncthreads();
}

// Register-weight matvec as a macro: rw must be a local float[64] accessed
// only with constant indices so it stays in VGPRs (no pointer decay).
// Identical FMA sequence to matvec<128> (ascending k, same combine order).
// pre/bias are pointer expressions or nullptr (folded at compile time).
#define MATVEC_REG(rw, srcp, pre, bias, dest)                        \
  do {                                                               \
    const float* sp_ = (srcp) + hv * 64;                             \
    float acc_ = 0.f;                                                \
    _Pragma("unroll")                                                \
    for (int k_ = 0; k_ < 64; k_ += 4) {                             \
      float4 s4_ = *reinterpret_cast<const float4*>(sp_ + k_);       \
      acc_ = fmaf(s4_.x, rw[k_ + 0], acc_);                          \
      acc_ = fmaf(s4_.y, rw[k_ + 1], acc_);                          \
      acc_ = fmaf(s4_.z, rw[k_ + 2], acc_);                          \
      acc_ = fmaf(s4_.w, rw[k_ + 3], acc_);                          \
    }                                                                \
    if (hv) s_part[j] = acc_;                                        \
    __syncthreads();                                                 \
    if (!hv) {                                                       \
      float r_ = acc_ + s_part[j];                                   \
      if (pre)  r_ += (pre)[j];                                      \
      if (bias) r_ += (bias)[j];                                     \
      (dest)[j] = r_;                                                \
    }                                                                \
    __syncthreads();                                                 \
  } while (0)

template<int RPH>
__device__ __forceinline__ void computeK(const float* __restrict__ W,
                                         const float* __restrict__ bias,
                                         const float* src, float* dst, int t) {
  const int j  = t & 127;
  const int hv = t >> 7;
  float acc[RPH];
#pragma unroll
  for (int s = 0; s < RPH; ++s) acc[s] = 0.f;
  const float* Wp = W + j;
#pragma unroll 4
  for (int k = 0; k < EDIM; ++k) {
    float w = Wp[(size_t)k * EDIM];
#pragma unroll
    for (int s = 0; s < RPH; ++s)
      acc[s] = fmaf(src[(hv + 2 * s) * EDIM + k], w, acc[s]);
  }
  float bj = bias[j];
#pragma unroll
  for (int s = 0; s < RPH; ++s) dst[(hv + 2 * s) * EDIM + j] = acc[s] + bj;
}

__global__ __launch_bounds__(THREADS, 2)
void decoder_kernel(const float* __restrict__ node_context,
                    const float* __restrict__ cell_context,
                    const float* __restrict__ original_data,
                    const float* __restrict__ high_mask,
                    const float* __restrict__ low_mask,
                    const float* __restrict__ init_w,
                    const float* __restrict__ W_hc,  const float* __restrict__ b_hc,
                    const float* __restrict__ W_vw,  const float* __restrict__ b_vw,
                    const float* __restrict__ Wq,    const float* __restrict__ bq,
                    const float* __restrict__ Wk,    const float* __restrict__ bk,
                    const float* __restrict__ v_hi,
                    const float* __restrict__ low_init_w,
                    const float* __restrict__ low_W_hc, const float* __restrict__ low_b_hc,
                    const float* __restrict__ low_W_vw, const float* __restrict__ low_b_vw,
                    const float* __restrict__ low_Wq,   const float* __restrict__ low_bq,
                    const float* __restrict__ low_Wk,   const float* __restrict__ low_bk,
                    const float* __restrict__ v_lo,
                    float* __restrict__ out) {
  const int b = blockIdx.x;
  const int t = threadIdx.x;
  const int j  = t & 127;
  const int hv = t >> 7;

  __shared__ float s_cc[NCELL][EDIM];
  __shared__ float s_Kh[NCELL][EDIM];
  __shared__ float s_emb[NNODE][EDIM];
  __shared__ float s_Kl[NNODE][EDIM];
  __shared__ float s_coords[NNODE][2];
  __shared__ float s_qh[EDIM], s_ql[EDIM], s_qq[EDIM];
  __shared__ float s_qbh[EDIM], s_qbl[EDIM];
  __shared__ float s_hbl[EDIM], s_hbh[EDIM];
  __shared__ float s_mean[EDIM], s_part[EDIM];
  __shared__ float s_vh[EDIM], s_vl[EDIM];
  __shared__ float s_bqh[EDIM], s_bql[EDIM];
  __shared__ float s_iw[2 * EDIM], s_iwl[2 * EDIM];
  __shared__ float s_u[NNODE];
  __shared__ float s_maskl[NNODE];
  __shared__ float s_maskh[NCELL];
  __shared__ uint32_t s_kh[NCELL][2];
  __shared__ uint32_t s_kl[NCELL][2];
  __shared__ uint32_t s_ks[NNODE][2];
  __shared__ uint32_t s_base[4];
#if !PARTITIONABLE
  __shared__ uint32_t s_tmp[4 * NCELL];
  __shared__ uint32_t s_ksp[2 * NNODE];
#endif
  __shared__ int s_idx;

  // ---- register-cached weights: ONLY constant-index accesses below ----
  float rwq[64];   // low_Wq[hv*64+k][j]
  float rwv[64];   // low_W_vw[128 + hv*64 + k][j]  (bottom half)
  {
    const float* gq = low_Wq + (size_t)(hv * 64) * EDIM + j;
    const float* gv = low_W_vw + (size_t)(128 + hv * 64) * EDIM + j;
#pragma unroll
    for (int k = 0; k < 64; ++k) rwq[k] = gq[(size_t)k * EDIM];
#pragma unroll
    for (int k = 0; k < 64; ++k) rwv[k] = gv[(size_t)k * EDIM];
  }

  // ---------------- key derivation ----------------
  if (t == 0) {
    uint32_t a0, a1;
    tf2x32(0u, 42u, 0u, 0u, a0, a1); s_base[0] = a0; s_base[1] = a1;
    tf2x32(0u, 42u, 0u, 1u, a0, a1); s_base[2] = a0; s_base[3] = a1;
  }
  __syncthreads();
#if PARTITIONABLE
  if (t < NCELL) {
    tf2x32(s_base[0], s_base[1], 0u, (uint32_t)t, s_kh[t][0], s_kh[t][1]);
    tf2x32(s_base[2], s_base[3], 0u, (uint32_t)t, s_kl[t][0], s_kl[t][1]);
  }
#else
  if (t < NCELL) {
    uint32_t o0, o1;
    tf2x32(s_base[0], s_base[1], (uint32_t)t, (uint32_t)(t + NCELL), o0, o1);
    s_tmp[t] = o0; s_tmp[t + NCELL] = o1;
    tf2x32(s_base[2], s_base[3], (uint32_t)t, (uint32_t)(t + NCELL), o0, o1);
    s_tmp[2 * NCELL + t] = o0; s_tmp[3 * NCELL + t] = o1;
  }
  __syncthreads();
  if (t < NCELL) {
    s_kh[t][0] = s_tmp[2 * t];              s_kh[t][1] = s_tmp[2 * t + 1];
    s_kl[t][0] = s_tmp[2 * NCELL + 2 * t];  s_kl[t][1] = s_tmp[2 * NCELL + 2 * t + 1];
  }
#endif

  // ---------------- block-level setup ----------------
  if (t < EDIM) {
    s_vh[t] = v_hi[t]; s_vl[t] = v_lo[t];
    s_bqh[t] = bq[t];  s_bql[t] = low_bq[t];
  }
  s_iw[t]  = init_w[t];
  s_iwl[t] = low_init_w[t];
  if (t < NCELL) s_maskh[t] = high_mask[b * NCELL + t];

  if (t < EDIM) {
    float s = 0.f;
    for (int n = 0; n < NCELL; ++n) {
      float x = cell_context[((size_t)b * NCELL + n) * EDIM + t];
      s_cc[n][t] = x; s += x;
    }
    s_mean[t] = s / 12.0f;
  }
  __syncthreads();
  matvec<128>(W_hc, s_mean, nullptr, b_hc, s_hbh, s_part, t);
  computeK<6>(Wk, bk, &s_cc[0][0], &s_Kh[0][0], t);
  __syncthreads();
  matvec<256>(W_vw, s_iw, s_hbh, b_vw, s_qh, s_part, t);
  if (t < EDIM) s_qbh[t] = s_hbh[t] + b_vw[t];
  __syncthreads();

  float cell_lp = 0.f, cell_rew = 0.f, lastx = 0.f, lasty = 0.f;

  for (int ci = 0; ci < NCELL; ++ci) {
    // ---- high attention scores
    matvec<128>(Wq, s_qh, nullptr, s_bqh, s_qq, s_part, t);
    if (t < 4 * NCELL) {
      int nd = t >> 2, p = t & 3, rot = t & 31;
      float acc = 0.f;
#pragma unroll 4
      for (int i2 = 0; i2 < 32; ++i2) {
        int h = p * 32 + ((i2 + rot) & 31);
        acc = fmaf(s_vh[h], xla_tanh(s_qq[h] + s_Kh[nd][h]), acc);
      }
      acc += __shfl_xor(acc, 1);
      acc += __shfl_xor(acc, 2);
      if (p == 0) s_u[nd] = acc;
    }
    __syncthreads();

    // ---- sample high cell (wave 0)
    if (t < 64) {
      float logit = -__builtin_huge_valf(), val = -__builtin_huge_valf();
      if (t < NCELL) {
        float lg = (s_maskh[t] > 0.f) ? -1e9f : 10.0f * xla_tanh(s_u[t]);
        logit = lg;
        uint32_t bits = draw_bits(s_kh[ci][0], s_kh[ci][1],
                                  (uint32_t)(b * NCELL + t), (uint32_t)(NB * NCELL));
        val = lg + bits_to_gumbel(bits);
      }
      int bidx = t;
#pragma unroll
      for (int d = 32; d; d >>= 1) {
        float oval = __shfl_xor(val, d);
        int   oidx = __shfl_xor(bidx, d);
        if (oval > val || (oval == val && oidx < bidx)) { val = oval; bidx = oidx; }
      }
      float mx = logit;
#pragma unroll
      for (int d = 32; d; d >>= 1) mx = fmaxf(mx, __shfl_xor(mx, d));
      float ex = (t < NCELL) ? expf(logit - mx) : 0.f;
#pragma unroll
      for (int d = 32; d; d >>= 1) ex += __shfl_xor(ex, d);
      float chosen = __shfl(logit, bidx);
      cell_lp += (chosen - mx) - logf(ex);
      if (t == 0) {
        s_idx = bidx;
        s_maskh[bidx] = 1.0f;
        out[OFF_CACT + b * NCELL + ci] = (float)bidx;
      }
    }
    __syncthreads();
    const int cidx = s_idx;

    // ---- next high query
    if (ci == 0)
      matvec<128>(W_vw, &s_cc[cidx][0], s_qbh, nullptr, s_qbh, s_part, t);
    if (ci < NCELL - 1)
      matvec<128>(W_vw + 128 * EDIM, &s_cc[cidx][0], s_qbh, nullptr, s_qh, s_part, t);

    // ---- stage selected cell
    const float* embg = node_context + (((size_t)b * NCELL + cidx) * NNODE) * EDIM;
    if (t < EDIM) {
      float s = 0.f;
      for (int n = 0; n < NNODE; ++n) {
        float x = embg[n * EDIM + t];
        s_emb[n][t] = x; s += x;
      }
      s_mean[t] = s / 40.0f;
    }
    if (t >= 128 && t < 208) {
      int q = t - 128;
      s_coords[q >> 1][q & 1] = original_data[(((size_t)b * NCELL + cidx) * NNODE) * 2 + q];
    }
    if (t >= 208 && t < 208 + NNODE) s_maskl[t - 208] = low_mask[b * NNODE + (t - 208)];
    __syncthreads();
    matvec<128>(low_W_hc, s_mean, nullptr, low_b_hc, s_hbl, s_part, t);
    computeK<20>(low_Wk, low_bk, &s_emb[0][0], &s_Kl[0][0], t);
#if PARTITIONABLE
    if (t < NNODE) tf2x32(s_kl[ci][0], s_kl[ci][1], 0u, (uint32_t)t, s_ks[t][0], s_ks[t][1]);
#else
    if (t < NNODE) {
      uint32_t o0, o1;
      tf2x32(s_kl[ci][0], s_kl[ci][1], (uint32_t)t, (uint32_t)(t + NNODE), o0, o1);
      s_ksp[t] = o0; s_ksp[t + NNODE] = o1;
    }
#endif
    __syncthreads();
#if !PARTITIONABLE
    if (t < NNODE) { s_ks[t][0] = s_ksp[2 * t]; s_ks[t][1] = s_ksp[2 * t + 1]; }
#endif
    matvec<256>(low_W_vw, s_iwl, s_hbl, low_b_vw, s_ql, s_part, t);
    if (t < EDIM) s_qbl[t] = s_hbl[t] + low_b_vw[t];
    __syncthreads();

    // ---------------- low decode: 40 steps ----------------
    float llp = 0.f, rew = 0.f, prevx = 0.f, prevy = 0.f, initx = 0.f, inity = 0.f;
    for (int st = 0; st < NNODE; ++st) {
      MATVEC_REG(rwq, s_ql, (const float*)nullptr, s_bql, s_qq);
      if (t < 160) {
        int nd = t >> 2, p = t & 3, rot = t & 31;
        float acc = 0.f;
#pragma unroll 4
        for (int i2 = 0; i2 < 32; ++i2) {
          int h = p * 32 + ((i2 + rot) & 31);
          acc = fmaf(s_vl[h], xla_tanh(s_qq[h] + s_Kl[nd][h]), acc);
        }
        acc += __shfl_xor(acc, 1);
        acc += __shfl_xor(acc, 2);
        if (p == 0) s_u[nd] = acc;
      }
      __syncthreads();

      if (t < 64) {
        float logit = -__builtin_huge_valf(), val = -__builtin_huge_valf();
        if (t < NNODE) {
          float lg = (s_maskl[t] > 0.f) ? -1e9f : 10.0f * xla_tanh(s_u[t]);
          logit = lg;
          uint32_t bits = draw_bits(s_ks[st][0], s_ks[st][1],
                                    (uint32_t)(b * NNODE + t), (uint32_t)(NB * NNODE));
          val = lg + bits_to_gumbel(bits);
        }
        int bidx = t;
#pragma unroll
        for (int d = 32; d; d >>= 1) {
          float oval = __shfl_xor(val, d);
          int   oidx = __shfl_xor(bidx, d);
          if (oval > val || (oval == val && oidx < bidx)) { val = oval; bidx = oidx; }
        }
        float mx = logit;
#pragma unroll
        for (int d = 32; d; d >>= 1) mx = fmaxf(mx, __shfl_xor(mx, d));
        float ex = (t < NNODE) ? expf(logit - mx) : 0.f;
#pragma unroll
        for (int d = 32; d; d >>= 1) ex += __shfl_xor(ex, d);
        float chosen = __shfl(logit, bidx);
        llp += (chosen - mx) - logf(ex);
        float cx = s_coords[bidx][0], cy = s_coords[bidx][1];
        if (st == 0) { initx = cx; inity = cy; }
        else { float dx = cx - prevx, dy = cy - prevy; rew += sqrtf(dx * dx + dy * dy); }
        prevx = cx; prevy = cy;
        if (t == 0) {
          s_idx = bidx;
          s_maskl[bidx] = 1.0f;
          out[OFF_NACT + ((size_t)(b * NCELL + ci)) * NNODE + st] = (float)bidx;
        }
      }
      __syncthreads();
      const int ni = s_idx;
      if (st == 0)
        matvec<128>(low_W_vw, &s_emb[ni][0], s_qbl, nullptr, s_qbl, s_part, t);
      if (st < NNODE - 1)
        MATVEC_REG(rwv, &s_emb[ni][0], s_qbl, (const float*)nullptr, s_ql);
    }

    // ---- finish cell
    if (t < 64) {
      if (ci > 0) {
        float dx = initx - lastx, dy = inity - lasty;
        cell_rew += sqrtf(dx * dx + dy * dy);
      }
      lastx = prevx; lasty = prevy;
      if (t == 0) {
        out[OFF_NLP + b * NCELL + ci] = llp;
        out[OFF_NRW + b * NCELL + ci] = rew;
      }
    }
  }

  if (t == 0) {
    out[OFF_CLP + b] = cell_lp;
    out[OFF_CRW + b] = cell_rew;
  }
}

extern "C" void kernel_launch(void* const* d_in, const int* in_sizes, int n_in,
                              void* d_out, int out_size, void* d_ws, size_t ws_size,
                              hipStream_t stream) {
  (void)in_sizes; (void)n_in; (void)out_size; (void)d_ws; (void)ws_size;
  decoder_kernel<<<NB, THREADS, 0, stream>>>(
      (const float*)d_in[0],  (const float*)d_in[1],  (const float*)d_in[2],
      (const float*)d_in[3],  (const float*)d_in[4],  (const float*)d_in[5],
      (const float*)d_in[6],  (const float*)d_in[7],  (const float*)d_in[8],
      (const float*)d_in[9],  (const float*)d_in[10], (const float*)d_in[11],
      (const float*)d_in[12], (const float*)d_in[13], (const float*)d_in[14],
      (const float*)d_in[15], (const float*)d_in[16], (const float*)d_in[17],
      (const float*)d_in[18], (const float*)d_in[19], (const float*)d_in[20],
      (const float*)d_in[21], (const float*)d_in[22], (const float*)d_in[23],
      (const float*)d_in[24],
      (float*)d_out);
}

// Round 4
// 3781.189 us; speedup vs baseline: 1.2088x; 1.0080x over previous
//
#include <hip/hip_runtime.h>
#include <stdint.h>

// ---------------------------------------------------------------------------
// Decoder_72516227826046: hierarchical pointer-net decoder, bit-faithful JAX
// threefry PRNG + gumbel-max categorical, fp32 throughout.
// One block per batch element (512 blocks x 256 threads).
// R4: amdgpu_waves_per_eu(2,2) pins the register allocator to the 256-VGPR
// budget (2 waves/EU) so the two 64-float weight arrays actually promote to
// VGPRs. R2/R3 spilled them to scratch (VGPR stuck at 128, WRITE_SIZE 33MB)
// because launch_bounds' second arg is only a MINIMUM — the allocator
// targeted 4 waves/EU. Also: argmax+max shuffle butterflies fused (two
// independent ds_permute chains overlap). All arithmetic orders unchanged.
// ---------------------------------------------------------------------------

#define PARTITIONABLE 1

#define NB    512
#define NCELL 12
#define NNODE 40
#define EDIM  128
#define THREADS 256

// output layout (all float32)
#define OFF_CLP  0                    // cell_log_prob [512]
#define OFF_NLP  512                  // node_log_prob [6144]
#define OFF_CRW  6656                 // cell_reward   [512]
#define OFF_NRW  7168                 // node_reward   [6144]
#define OFF_CACT 13312                // cell_action   [6144]
#define OFF_NACT 19456                // node_action   [245760]

// ---------------- threefry2x32 (bit-exact vs jax._src.prng) ----------------
__device__ __forceinline__ uint32_t rotl32(uint32_t x, int d) {
  return (x << d) | (x >> (32 - d));
}

__device__ __forceinline__ void tf2x32(uint32_t k0, uint32_t k1,
                                       uint32_t c0, uint32_t c1,
                                       uint32_t& o0, uint32_t& o1) {
  uint32_t ks2 = k0 ^ k1 ^ 0x1BD11BDAu;
  uint32_t x0 = c0 + k0, x1 = c1 + k1;
#define TFR(r) { x0 += x1; x1 = rotl32(x1, (r)); x1 ^= x0; }
  TFR(13) TFR(15) TFR(26) TFR(6)   x0 += k1;  x1 += ks2 + 1u;
  TFR(17) TFR(29) TFR(16) TFR(24)  x0 += ks2; x1 += k0 + 2u;
  TFR(13) TFR(15) TFR(26) TFR(6)   x0 += k0;  x1 += k1 + 3u;
  TFR(17) TFR(29) TFR(16) TFR(24)  x0 += k1;  x1 += ks2 + 4u;
  TFR(13) TFR(15) TFR(26) TFR(6)   x0 += ks2; x1 += k0 + 5u;
#undef TFR
  o0 = x0; o1 = x1;
}

__device__ __forceinline__ uint32_t draw_bits(uint32_t k0, uint32_t k1,
                                              uint32_t idx, uint32_t total) {
  uint32_t o0, o1;
#if PARTITIONABLE
  (void)total;
  tf2x32(k0, k1, 0u, idx, o0, o1);
  return o0 ^ o1;
#else
  uint32_t hlf = total >> 1;
  if (idx < hlf) { tf2x32(k0, k1, idx, idx + hlf, o0, o1); return o0; }
  tf2x32(k0, k1, idx - hlf, idx, o0, o1); return o1;
#endif
}

__device__ __forceinline__ float bits_to_gumbel(uint32_t bits) {
  uint32_t fb = (bits >> 9) | 0x3F800000u;
  float f = __uint_as_float(fb) - 1.0f;            // [0,1)
  const float TINY = 1.17549435082228751e-38f;
  float u = f * (1.0f - TINY) + TINY;
  u = fmaxf(TINY, u);
  return -logf(-logf(u));
}

__device__ __forceinline__ float xla_tanh(float x) {
#pragma clang fp contract(off)
  float ax = fabsf(x);
  float xc = fminf(fmaxf(x, -9.0f), 9.0f);
  float x2 = xc * xc;
  float nm = -2.76076847742355e-16f;
  nm = nm * x2 + 2.00018790482477e-13f;
  nm = nm * x2 + -8.60467152213735e-11f;
  nm = nm * x2 + 5.12229709037114e-08f;
  nm = nm * x2 + 1.48572235717979e-05f;
  nm = nm * x2 + 6.37261928875436e-04f;
  nm = nm * x2 + 4.89352455891786e-03f;
  nm = xc * nm;
  float dn = 1.19825839466702e-06f;
  dn = dn * x2 + 1.18534705686654e-04f;
  dn = dn * x2 + 2.26843463243900e-03f;
  dn = dn * x2 + 4.89352518554385e-03f;
  return (ax < 0.0004f) ? x : (nm / dn);
}

// pointer-based matvec (setup/high-level path)
template<int KLEN>
__device__ __forceinline__ void matvec(const float* __restrict__ W,
                                       const float* __restrict__ src,
                                       const float* __restrict__ pre,
                                       const float* __restrict__ bias,
                                       float* dest, float* part, int t) {
  const int j  = t & 127;
  const int hv = t >> 7;
  const int kh = KLEN / 2;
  const int k0 = hv * kh;
  float acc = 0.f;
  const float* Wp = W + (size_t)k0 * EDIM + j;
  const float* sp = src + k0;
#pragma unroll 8
  for (int k = 0; k < kh; ++k) acc = fmaf(sp[k], Wp[(size_t)k * EDIM], acc);
  if (hv) part[j] = acc;
  __syncthreads();
  if (!hv) {
    float r = acc + part[j];
    if (pre)  r += pre[j];
    if (bias) r += bias[j];
    dest[j] = r;
  }
  __syncthreads();
}

// Register-weight matvec as a macro: rw must be a local float[64] accessed
// only with constant indices so it stays in VGPRs (no pointer decay).
// Identical FMA sequence to matvec<128> (ascending k, same combine order).
#define MATVEC_REG(rw, srcp, pre, bias, dest)                        \
  do {                                                               \
    const float* sp_ = (srcp) + hv * 64;                             \
    float acc_ = 0.f;                                                \
    _Pragma("unroll")                                                \
    for (int k_ = 0; k_ < 64; k_ += 4) {                             \
      float4 s4_ = *reinterpret_cast<const float4*>(sp_ + k_);       \
      acc_ = fmaf(s4_.x, rw[k_ + 0], acc_);                          \
      acc_ = fmaf(s4_.y, rw[k_ + 1], acc_);                          \
      acc_ = fmaf(s4_.z, rw[k_ + 2], acc_);                          \
      acc_ = fmaf(s4_.w, rw[k_ + 3], acc_);                          \
    }                                                                \
    if (hv) s_part[j] = acc_;                                        \
    __syncthreads();                                                 \
    if (!hv) {                                                       \
      float r_ = acc_ + s_part[j];                                   \
      if (pre)  r_ += (pre)[j];                                      \
      if (bias) r_ += (bias)[j];                                     \
      (dest)[j] = r_;                                                \
    }                                                                \
    __syncthreads();                                                 \
  } while (0)

template<int RPH>
__device__ __forceinline__ void computeK(const float* __restrict__ W,
                                         const float* __restrict__ bias,
                                         const float* src, float* dst, int t) {
  const int j  = t & 127;
  const int hv = t >> 7;
  float acc[RPH];
#pragma unroll
  for (int s = 0; s < RPH; ++s) acc[s] = 0.f;
  const float* Wp = W + j;
#pragma unroll 4
  for (int k = 0; k < EDIM; ++k) {
    float w = Wp[(size_t)k * EDIM];
#pragma unroll
    for (int s = 0; s < RPH; ++s)
      acc[s] = fmaf(src[(hv + 2 * s) * EDIM + k], w, acc[s]);
  }
  float bj = bias[j];
#pragma unroll
  for (int s = 0; s < RPH; ++s) dst[(hv + 2 * s) * EDIM + j] = acc[s] + bj;
}

__global__ __launch_bounds__(THREADS)
__attribute__((amdgpu_waves_per_eu(2, 2)))
void decoder_kernel(const float* __restrict__ node_context,
                    const float* __restrict__ cell_context,
                    const float* __restrict__ original_data,
                    const float* __restrict__ high_mask,
                    const float* __restrict__ low_mask,
                    const float* __restrict__ init_w,
                    const float* __restrict__ W_hc,  const float* __restrict__ b_hc,
                    const float* __restrict__ W_vw,  const float* __restrict__ b_vw,
                    const float* __restrict__ Wq,    const float* __restrict__ bq,
                    const float* __restrict__ Wk,    const float* __restrict__ bk,
                    const float* __restrict__ v_hi,
                    const float* __restrict__ low_init_w,
                    const float* __restrict__ low_W_hc, const float* __restrict__ low_b_hc,
                    const float* __restrict__ low_W_vw, const float* __restrict__ low_b_vw,
                    const float* __restrict__ low_Wq,   const float* __restrict__ low_bq,
                    const float* __restrict__ low_Wk,   const float* __restrict__ low_bk,
                    const float* __restrict__ v_lo,
                    float* __restrict__ out) {
  const int b = blockIdx.x;
  const int t = threadIdx.x;
  const int j  = t & 127;
  const int hv = t >> 7;

  __shared__ float s_cc[NCELL][EDIM];
  __shared__ float s_Kh[NCELL][EDIM];
  __shared__ float s_emb[NNODE][EDIM];
  __shared__ float s_Kl[NNODE][EDIM];
  __shared__ float s_coords[NNODE][2];
  __shared__ float s_qh[EDIM], s_ql[EDIM], s_qq[EDIM];
  __shared__ float s_qbh[EDIM], s_qbl[EDIM];
  __shared__ float s_hbl[EDIM], s_hbh[EDIM];
  __shared__ float s_mean[EDIM], s_part[EDIM];
  __shared__ float s_vh[EDIM], s_vl[EDIM];
  __shared__ float s_bqh[EDIM], s_bql[EDIM];
  __shared__ float s_iw[2 * EDIM], s_iwl[2 * EDIM];
  __shared__ float s_u[NNODE];
  __shared__ float s_maskl[NNODE];
  __shared__ float s_maskh[NCELL];
  __shared__ uint32_t s_kh[NCELL][2];
  __shared__ uint32_t s_kl[NCELL][2];
  __shared__ uint32_t s_ks[NNODE][2];
  __shared__ uint32_t s_base[4];
#if !PARTITIONABLE
  __shared__ uint32_t s_tmp[4 * NCELL];
  __shared__ uint32_t s_ksp[2 * NNODE];
#endif
  __shared__ int s_idx;

  // ---- register-cached weights: ONLY constant-index accesses below ----
  float rwq[64];   // low_Wq[hv*64+k][j]
  float rwv[64];   // low_W_vw[128 + hv*64 + k][j]  (bottom half)
  {
    const float* gq = low_Wq + (size_t)(hv * 64) * EDIM + j;
    const float* gv = low_W_vw + (size_t)(128 + hv * 64) * EDIM + j;
#pragma unroll
    for (int k = 0; k < 64; ++k) rwq[k] = gq[(size_t)k * EDIM];
#pragma unroll
    for (int k = 0; k < 64; ++k) rwv[k] = gv[(size_t)k * EDIM];
  }

  // ---------------- key derivation ----------------
  if (t == 0) {
    uint32_t a0, a1;
    tf2x32(0u, 42u, 0u, 0u, a0, a1); s_base[0] = a0; s_base[1] = a1;
    tf2x32(0u, 42u, 0u, 1u, a0, a1); s_base[2] = a0; s_base[3] = a1;
  }
  __syncthreads();
#if PARTITIONABLE
  if (t < NCELL) {
    tf2x32(s_base[0], s_base[1], 0u, (uint32_t)t, s_kh[t][0], s_kh[t][1]);
    tf2x32(s_base[2], s_base[3], 0u, (uint32_t)t, s_kl[t][0], s_kl[t][1]);
  }
#else
  if (t < NCELL) {
    uint32_t o0, o1;
    tf2x32(s_base[0], s_base[1], (uint32_t)t, (uint32_t)(t + NCELL), o0, o1);
    s_tmp[t] = o0; s_tmp[t + NCELL] = o1;
    tf2x32(s_base[2], s_base[3], (uint32_t)t, (uint32_t)(t + NCELL), o0, o1);
    s_tmp[2 * NCELL + t] = o0; s_tmp[3 * NCELL + t] = o1;
  }
  __syncthreads();
  if (t < NCELL) {
    s_kh[t][0] = s_tmp[2 * t];              s_kh[t][1] = s_tmp[2 * t + 1];
    s_kl[t][0] = s_tmp[2 * NCELL + 2 * t];  s_kl[t][1] = s_tmp[2 * NCELL + 2 * t + 1];
  }
#endif

  // ---------------- block-level setup ----------------
  if (t < EDIM) {
    s_vh[t] = v_hi[t]; s_vl[t] = v_lo[t];
    s_bqh[t] = bq[t];  s_bql[t] = low_bq[t];
  }
  s_iw[t]  = init_w[t];
  s_iwl[t] = low_init_w[t];
  if (t < NCELL) s_maskh[t] = high_mask[b * NCELL + t];

  if (t < EDIM) {
    float s = 0.f;
    for (int n = 0; n < NCELL; ++n) {
      float x = cell_context[((size_t)b * NCELL + n) * EDIM + t];
      s_cc[n][t] = x; s += x;
    }
    s_mean[t] = s / 12.0f;
  }
  __syncthreads();
  matvec<128>(W_hc, s_mean, nullptr, b_hc, s_hbh, s_part, t);
  computeK<6>(Wk, bk, &s_cc[0][0], &s_Kh[0][0], t);
  __syncthreads();
  matvec<256>(W_vw, s_iw, s_hbh, b_vw, s_qh, s_part, t);
  if (t < EDIM) s_qbh[t] = s_hbh[t] + b_vw[t];
  __syncthreads();

  float cell_lp = 0.f, cell_rew = 0.f, lastx = 0.f, lasty = 0.f;

  for (int ci = 0; ci < NCELL; ++ci) {
    // ---- high attention scores
    matvec<128>(Wq, s_qh, nullptr, s_bqh, s_qq, s_part, t);
    if (t < 4 * NCELL) {
      int nd = t >> 2, p = t & 3, rot = t & 31;
      float acc = 0.f;
#pragma unroll 4
      for (int i2 = 0; i2 < 32; ++i2) {
        int h = p * 32 + ((i2 + rot) & 31);
        acc = fmaf(s_vh[h], xla_tanh(s_qq[h] + s_Kh[nd][h]), acc);
      }
      acc += __shfl_xor(acc, 1);
      acc += __shfl_xor(acc, 2);
      if (p == 0) s_u[nd] = acc;
    }
    __syncthreads();

    // ---- sample high cell (wave 0)
    if (t < 64) {
      float logit = -__builtin_huge_valf(), val = -__builtin_huge_valf();
      if (t < NCELL) {
        float lg = (s_maskh[t] > 0.f) ? -1e9f : 10.0f * xla_tanh(s_u[t]);
        logit = lg;
        uint32_t bits = draw_bits(s_kh[ci][0], s_kh[ci][1],
                                  (uint32_t)(b * NCELL + t), (uint32_t)(NB * NCELL));
        val = lg + bits_to_gumbel(bits);
      }
      int bidx = t;
      float mx = logit;
#pragma unroll
      for (int d = 32; d; d >>= 1) {          // fused argmax + max butterflies
        float oval = __shfl_xor(val, d);
        int   oidx = __shfl_xor(bidx, d);
        float omx  = __shfl_xor(mx, d);
        if (oval > val || (oval == val && oidx < bidx)) { val = oval; bidx = oidx; }
        mx = fmaxf(mx, omx);
      }
      float ex = (t < NCELL) ? expf(logit - mx) : 0.f;
#pragma unroll
      for (int d = 32; d; d >>= 1) ex += __shfl_xor(ex, d);
      float chosen = __shfl(logit, bidx);
      cell_lp += (chosen - mx) - logf(ex);
      if (t == 0) {
        s_idx = bidx;
        s_maskh[bidx] = 1.0f;
        out[OFF_CACT + b * NCELL + ci] = (float)bidx;
      }
    }
    __syncthreads();
    const int cidx = s_idx;

    // ---- next high query
    if (ci == 0)
      matvec<128>(W_vw, &s_cc[cidx][0], s_qbh, nullptr, s_qbh, s_part, t);
    if (ci < NCELL - 1)
      matvec<128>(W_vw + 128 * EDIM, &s_cc[cidx][0], s_qbh, nullptr, s_qh, s_part, t);

    // ---- stage selected cell
    const float* embg = node_context + (((size_t)b * NCELL + cidx) * NNODE) * EDIM;
    if (t < EDIM) {
      float s = 0.f;
      for (int n = 0; n < NNODE; ++n) {
        float x = embg[n * EDIM + t];
        s_emb[n][t] = x; s += x;
      }
      s_mean[t] = s / 40.0f;
    }
    if (t >= 128 && t < 208) {
      int q = t - 128;
      s_coords[q >> 1][q & 1] = original_data[(((size_t)b * NCELL + cidx) * NNODE) * 2 + q];
    }
    if (t >= 208 && t < 208 + NNODE) s_maskl[t - 208] = low_mask[b * NNODE + (t - 208)];
    __syncthreads();
    matvec<128>(low_W_hc, s_mean, nullptr, low_b_hc, s_hbl, s_part, t);
    computeK<20>(low_Wk, low_bk, &s_emb[0][0], &s_Kl[0][0], t);
#if PARTITIONABLE
    if (t < NNODE) tf2x32(s_kl[ci][0], s_kl[ci][1], 0u, (uint32_t)t, s_ks[t][0], s_ks[t][1]);
#else
    if (t < NNODE) {
      uint32_t o0, o1;
      tf2x32(s_kl[ci][0], s_kl[ci][1], (uint32_t)t, (uint32_t)(t + NNODE), o0, o1);
      s_ksp[t] = o0; s_ksp[t + NNODE] = o1;
    }
#endif
    __syncthreads();
#if !PARTITIONABLE
    if (t < NNODE) { s_ks[t][0] = s_ksp[2 * t]; s_ks[t][1] = s_ksp[2 * t + 1]; }
#endif
    matvec<256>(low_W_vw, s_iwl, s_hbl, low_b_vw, s_ql, s_part, t);
    if (t < EDIM) s_qbl[t] = s_hbl[t] + low_b_vw[t];
    __syncthreads();

    // ---------------- low decode: 40 steps ----------------
    float llp = 0.f, rew = 0.f, prevx = 0.f, prevy = 0.f, initx = 0.f, inity = 0.f;
    for (int st = 0; st < NNODE; ++st) {
      MATVEC_REG(rwq, s_ql, (const float*)nullptr, s_bql, s_qq);
      if (t < 160) {
        int nd = t >> 2, p = t & 3, rot = t & 31;
        float acc = 0.f;
#pragma unroll 4
        for (int i2 = 0; i2 < 32; ++i2) {
          int h = p * 32 + ((i2 + rot) & 31);
          acc = fmaf(s_vl[h], xla_tanh(s_qq[h] + s_Kl[nd][h]), acc);
        }
        acc += __shfl_xor(acc, 1);
        acc += __shfl_xor(acc, 2);
        if (p == 0) s_u[nd] = acc;
      }
      __syncthreads();

      if (t < 64) {
        float logit = -__builtin_huge_valf(), val = -__builtin_huge_valf();
        if (t < NNODE) {
          float lg = (s_maskl[t] > 0.f) ? -1e9f : 10.0f * xla_tanh(s_u[t]);
          logit = lg;
          uint32_t bits = draw_bits(s_ks[st][0], s_ks[st][1],
                                    (uint32_t)(b * NNODE + t), (uint32_t)(NB * NNODE));
          val = lg + bits_to_gumbel(bits);
        }
        int bidx = t;
        float mx = logit;
#pragma unroll
        for (int d = 32; d; d >>= 1) {        // fused argmax + max butterflies
          float oval = __shfl_xor(val, d);
          int   oidx = __shfl_xor(bidx, d);
          float omx  = __shfl_xor(mx, d);
          if (oval > val || (oval == val && oidx < bidx)) { val = oval; bidx = oidx; }
          mx = fmaxf(mx, omx);
        }
        float ex = (t < NNODE) ? expf(logit - mx) : 0.f;
#pragma unroll
        for (int d = 32; d; d >>= 1) ex += __shfl_xor(ex, d);
        float chosen = __shfl(logit, bidx);
        llp += (chosen - mx) - logf(ex);
        float cx = s_coords[bidx][0], cy = s_coords[bidx][1];
        if (st == 0) { initx = cx; inity = cy; }
        else { float dx = cx - prevx, dy = cy - prevy; rew += sqrtf(dx * dx + dy * dy); }
        prevx = cx; prevy = cy;
        if (t == 0) {
          s_idx = bidx;
          s_maskl[bidx] = 1.0f;
          out[OFF_NACT + ((size_t)(b * NCELL + ci)) * NNODE + st] = (float)bidx;
        }
      }
      __syncthreads();
      const int ni = s_idx;
      if (st == 0)
        matvec<128>(low_W_vw, &s_emb[ni][0], s_qbl, nullptr, s_qbl, s_part, t);
      if (st < NNODE - 1)
        MATVEC_REG(rwv, &s_emb[ni][0], s_qbl, (const float*)nullptr, s_ql);
    }

    // ---- finish cell
    if (t < 64) {
      if (ci > 0) {
        float dx = initx - lastx, dy = inity - lasty;
        cell_rew += sqrtf(dx * dx + dy * dy);
      }
      lastx = prevx; lasty = prevy;
      if (t == 0) {
        out[OFF_NLP + b * NCELL + ci] = llp;
        out[OFF_NRW + b * NCELL + ci] = rew;
      }
    }
  }

  if (t == 0) {
    out[OFF_CLP + b] = cell_lp;
    out[OFF_CRW + b] = cell_rew;
  }
}

extern "C" void kernel_launch(void* const* d_in, const int* in_sizes, int n_in,
                              void* d_out, int out_size, void* d_ws, size_t ws_size,
                              hipStream_t stream) {
  (void)in_sizes; (void)n_in; (void)out_size; (void)d_ws; (void)ws_size;
  decoder_kernel<<<NB, THREADS, 0, stream>>>(
      (const float*)d_in[0],  (const float*)d_in[1],  (const float*)d_in[2],
      (const float*)d_in[3],  (const float*)d_in[4],  (const float*)d_in[5],
      (const float*)d_in[6],  (const float*)d_in[7],  (const float*)d_in[8],
      (const float*)d_in[9],  (const float*)d_in[10], (const float*)d_in[11],
      (const float*)d_in[12], (const float*)d_in[13], (const float*)d_in[14],
      (const float*)d_in[15], (const float*)d_in[16], (const float*)d_in[17],
      (const float*)d_in[18], (const float*)d_in[19], (const float*)d_in[20],
      (const float*)d_in[21], (const float*)d_in[22], (const float*)d_in[23],
      (const float*)d_in[24],
      (float*)d_out);
}

// Round 5
// 3749.581 us; speedup vs baseline: 1.2190x; 1.0084x over previous
//
#include <hip/hip_runtime.h>
#include <stdint.h>

// ---------------------------------------------------------------------------
// Decoder_72516227826046: hierarchical pointer-net decoder, bit-faithful JAX
// threefry PRNG + gumbel-max categorical, fp32 throughout.
// One block per batch element (512 blocks x 256 threads).
// R5: weight register-cache via ext_vector_type(16) x4 per matrix, accessed
// ONLY with literal indices (macro-expanded). float[64] arrays failed in
// R2-R4 because SROA runs before loop unrolling -> scratch alloca (VGPR
// stuck at 128, WRITE_SIZE 33MB). Vectors are first-class SSA: no alloca.
// FMA order is bit-identical to the passing kernels (ascending k, half0+
// half1+pre+bias combine).
// ---------------------------------------------------------------------------

#define PARTITIONABLE 1

#define NB    512
#define NCELL 12
#define NNODE 40
#define EDIM  128
#define THREADS 256

// output layout (all float32)
#define OFF_CLP  0                    // cell_log_prob [512]
#define OFF_NLP  512                  // node_log_prob [6144]
#define OFF_CRW  6656                 // cell_reward   [512]
#define OFF_NRW  7168                 // node_reward   [6144]
#define OFF_CACT 13312                // cell_action   [6144]
#define OFF_NACT 19456                // node_action   [245760]

typedef float f32x16 __attribute__((ext_vector_type(16)));

// ---------------- threefry2x32 (bit-exact vs jax._src.prng) ----------------
__device__ __forceinline__ uint32_t rotl32(uint32_t x, int d) {
  return (x << d) | (x >> (32 - d));
}

__device__ __forceinline__ void tf2x32(uint32_t k0, uint32_t k1,
                                       uint32_t c0, uint32_t c1,
                                       uint32_t& o0, uint32_t& o1) {
  uint32_t ks2 = k0 ^ k1 ^ 0x1BD11BDAu;
  uint32_t x0 = c0 + k0, x1 = c1 + k1;
#define TFR(r) { x0 += x1; x1 = rotl32(x1, (r)); x1 ^= x0; }
  TFR(13) TFR(15) TFR(26) TFR(6)   x0 += k1;  x1 += ks2 + 1u;
  TFR(17) TFR(29) TFR(16) TFR(24)  x0 += ks2; x1 += k0 + 2u;
  TFR(13) TFR(15) TFR(26) TFR(6)   x0 += k0;  x1 += k1 + 3u;
  TFR(17) TFR(29) TFR(16) TFR(24)  x0 += k1;  x1 += ks2 + 4u;
  TFR(13) TFR(15) TFR(26) TFR(6)   x0 += ks2; x1 += k0 + 5u;
#undef TFR
  o0 = x0; o1 = x1;
}

__device__ __forceinline__ uint32_t draw_bits(uint32_t k0, uint32_t k1,
                                              uint32_t idx, uint32_t total) {
  uint32_t o0, o1;
#if PARTITIONABLE
  (void)total;
  tf2x32(k0, k1, 0u, idx, o0, o1);
  return o0 ^ o1;
#else
  uint32_t hlf = total >> 1;
  if (idx < hlf) { tf2x32(k0, k1, idx, idx + hlf, o0, o1); return o0; }
  tf2x32(k0, k1, idx - hlf, idx, o0, o1); return o1;
#endif
}

__device__ __forceinline__ float bits_to_gumbel(uint32_t bits) {
  uint32_t fb = (bits >> 9) | 0x3F800000u;
  float f = __uint_as_float(fb) - 1.0f;            // [0,1)
  const float TINY = 1.17549435082228751e-38f;
  float u = f * (1.0f - TINY) + TINY;
  u = fmaxf(TINY, u);
  return -logf(-logf(u));
}

__device__ __forceinline__ float xla_tanh(float x) {
#pragma clang fp contract(off)
  float ax = fabsf(x);
  float xc = fminf(fmaxf(x, -9.0f), 9.0f);
  float x2 = xc * xc;
  float nm = -2.76076847742355e-16f;
  nm = nm * x2 + 2.00018790482477e-13f;
  nm = nm * x2 + -8.60467152213735e-11f;
  nm = nm * x2 + 5.12229709037114e-08f;
  nm = nm * x2 + 1.48572235717979e-05f;
  nm = nm * x2 + 6.37261928875436e-04f;
  nm = nm * x2 + 4.89352455891786e-03f;
  nm = xc * nm;
  float dn = 1.19825839466702e-06f;
  dn = dn * x2 + 1.18534705686654e-04f;
  dn = dn * x2 + 2.26843463243900e-03f;
  dn = dn * x2 + 4.89352518554385e-03f;
  return (ax < 0.0004f) ? x : (nm / dn);
}

// pointer-based matvec (setup/high-level path)
template<int KLEN>
__device__ __forceinline__ void matvec(const float* __restrict__ W,
                                       const float* __restrict__ src,
                                       const float* __restrict__ pre,
                                       const float* __restrict__ bias,
                                       float* dest, float* part, int t) {
  const int j  = t & 127;
  const int hv = t >> 7;
  const int kh = KLEN / 2;
  const int k0 = hv * kh;
  float acc = 0.f;
  const float* Wp = W + (size_t)k0 * EDIM + j;
  const float* sp = src + k0;
#pragma unroll 8
  for (int k = 0; k < kh; ++k) acc = fmaf(sp[k], Wp[(size_t)k * EDIM], acc);
  if (hv) part[j] = acc;
  __syncthreads();
  if (!hv) {
    float r = acc + part[j];
    if (pre)  r += pre[j];
    if (bias) r += bias[j];
    dest[j] = r;
  }
  __syncthreads();
}

// ---- literal-index weight-vector load (no alloca, pure insertelement) ----
#define LD1(vec,i,gp,base) (vec)[i] = (gp)[(size_t)((base)+(i))*EDIM];
#define LD16(vec,gp,base)                                                   \
  LD1(vec,0,gp,base)  LD1(vec,1,gp,base)  LD1(vec,2,gp,base)  LD1(vec,3,gp,base)  \
  LD1(vec,4,gp,base)  LD1(vec,5,gp,base)  LD1(vec,6,gp,base)  LD1(vec,7,gp,base)  \
  LD1(vec,8,gp,base)  LD1(vec,9,gp,base)  LD1(vec,10,gp,base) LD1(vec,11,gp,base) \
  LD1(vec,12,gp,base) LD1(vec,13,gp,base) LD1(vec,14,gp,base) LD1(vec,15,gp,base)

// ---- literal-index register matvec, FMA order identical to matvec<128> ----
#define FMA4(vec,i0,spp)                                             \
  { float4 s4_ = *reinterpret_cast<const float4*>(spp);              \
    acc_ = fmaf(s4_.x, (vec)[(i0)+0], acc_);                         \
    acc_ = fmaf(s4_.y, (vec)[(i0)+1], acc_);                         \
    acc_ = fmaf(s4_.z, (vec)[(i0)+2], acc_);                         \
    acc_ = fmaf(s4_.w, (vec)[(i0)+3], acc_); }
#define FMA16(vec,spb) FMA4(vec,0,(spb)+0) FMA4(vec,4,(spb)+4)       \
                       FMA4(vec,8,(spb)+8) FMA4(vec,12,(spb)+12)

#define MATVEC_REGV(v0,v1,v2,v3, srcp, pre, bias, dest)              \
  do {                                                               \
    const float* sp_ = (srcp) + hv * 64;                             \
    float acc_ = 0.f;                                                \
    FMA16(v0, sp_) FMA16(v1, sp_+16) FMA16(v2, sp_+32) FMA16(v3, sp_+48) \
    if (hv) s_part[j] = acc_;                                        \
    __syncthreads();                                                 \
    if (!hv) {                                                       \
      float r_ = acc_ + s_part[j];                                   \
      if (pre)  r_ += (pre)[j];                                      \
      if (bias) r_ += (bias)[j];                                     \
      (dest)[j] = r_;                                                \
    }                                                                \
    __syncthreads();                                                 \
  } while (0)

template<int RPH>
__device__ __forceinline__ void computeK(const float* __restrict__ W,
                                         const float* __restrict__ bias,
                                         const float* src, float* dst, int t) {
  const int j  = t & 127;
  const int hv = t >> 7;
  float acc[RPH];
#pragma unroll
  for (int s = 0; s < RPH; ++s) acc[s] = 0.f;
  const float* Wp = W + j;
#pragma unroll 4
  for (int k = 0; k < EDIM; ++k) {
    float w = Wp[(size_t)k * EDIM];
#pragma unroll
    for (int s = 0; s < RPH; ++s)
      acc[s] = fmaf(src[(hv + 2 * s) * EDIM + k], w, acc[s]);
  }
  float bj = bias[j];
#pragma unroll
  for (int s = 0; s < RPH; ++s) dst[(hv + 2 * s) * EDIM + j] = acc[s] + bj;
}

__global__ __launch_bounds__(THREADS, 2)
void decoder_kernel(const float* __restrict__ node_context,
                    const float* __restrict__ cell_context,
                    const float* __restrict__ original_data,
                    const float* __restrict__ high_mask,
                    const float* __restrict__ low_mask,
                    const float* __restrict__ init_w,
                    const float* __restrict__ W_hc,  const float* __restrict__ b_hc,
                    const float* __restrict__ W_vw,  const float* __restrict__ b_vw,
                    const float* __restrict__ Wq,    const float* __restrict__ bq,
                    const float* __restrict__ Wk,    const float* __restrict__ bk,
                    const float* __restrict__ v_hi,
                    const float* __restrict__ low_init_w,
                    const float* __restrict__ low_W_hc, const float* __restrict__ low_b_hc,
                    const float* __restrict__ low_W_vw, const float* __restrict__ low_b_vw,
                    const float* __restrict__ low_Wq,   const float* __restrict__ low_bq,
                    const float* __restrict__ low_Wk,   const float* __restrict__ low_bk,
                    const float* __restrict__ v_lo,
                    float* __restrict__ out) {
  const int b = blockIdx.x;
  const int t = threadIdx.x;
  const int j  = t & 127;
  const int hv = t >> 7;

  __shared__ float s_cc[NCELL][EDIM];
  __shared__ float s_Kh[NCELL][EDIM];
  __shared__ float s_emb[NNODE][EDIM];
  __shared__ float s_Kl[NNODE][EDIM];
  __shared__ float s_coords[NNODE][2];
  __shared__ float s_qh[EDIM], s_ql[EDIM], s_qq[EDIM];
  __shared__ float s_qbh[EDIM], s_qbl[EDIM];
  __shared__ float s_hbl[EDIM], s_hbh[EDIM];
  __shared__ float s_mean[EDIM], s_part[EDIM];
  __shared__ float s_vh[EDIM], s_vl[EDIM];
  __shared__ float s_bqh[EDIM], s_bql[EDIM];
  __shared__ float s_iw[2 * EDIM], s_iwl[2 * EDIM];
  __shared__ float s_u[NNODE];
  __shared__ float s_maskl[NNODE];
  __shared__ float s_maskh[NCELL];
  __shared__ uint32_t s_kh[NCELL][2];
  __shared__ uint32_t s_kl[NCELL][2];
  __shared__ uint32_t s_ks[NNODE][2];
  __shared__ uint32_t s_base[4];
#if !PARTITIONABLE
  __shared__ uint32_t s_tmp[4 * NCELL];
  __shared__ uint32_t s_ksp[2 * NNODE];
#endif
  __shared__ int s_idx;

  // ---- register-cached weights: vectors, literal indices only ----
  f32x16 rq0, rq1, rq2, rq3;   // low_Wq[hv*64 + k][j],        k = 0..63
  f32x16 rv0, rv1, rv2, rv3;   // low_W_vw[128 + hv*64 + k][j], k = 0..63
  {
    const float* gq = low_Wq + (size_t)(hv * 64) * EDIM + j;
    const float* gv = low_W_vw + (size_t)(128 + hv * 64) * EDIM + j;
    LD16(rq0, gq, 0)  LD16(rq1, gq, 16) LD16(rq2, gq, 32) LD16(rq3, gq, 48)
    LD16(rv0, gv, 0)  LD16(rv1, gv, 16) LD16(rv2, gv, 32) LD16(rv3, gv, 48)
  }

  // ---------------- key derivation ----------------
  if (t == 0) {
    uint32_t a0, a1;
    tf2x32(0u, 42u, 0u, 0u, a0, a1); s_base[0] = a0; s_base[1] = a1;
    tf2x32(0u, 42u, 0u, 1u, a0, a1); s_base[2] = a0; s_base[3] = a1;
  }
  __syncthreads();
#if PARTITIONABLE
  if (t < NCELL) {
    tf2x32(s_base[0], s_base[1], 0u, (uint32_t)t, s_kh[t][0], s_kh[t][1]);
    tf2x32(s_base[2], s_base[3], 0u, (uint32_t)t, s_kl[t][0], s_kl[t][1]);
  }
#else
  if (t < NCELL) {
    uint32_t o0, o1;
    tf2x32(s_base[0], s_base[1], (uint32_t)t, (uint32_t)(t + NCELL), o0, o1);
    s_tmp[t] = o0; s_tmp[t + NCELL] = o1;
    tf2x32(s_base[2], s_base[3], (uint32_t)t, (uint32_t)(t + NCELL), o0, o1);
    s_tmp[2 * NCELL + t] = o0; s_tmp[3 * NCELL + t] = o1;
  }
  __syncthreads();
  if (t < NCELL) {
    s_kh[t][0] = s_tmp[2 * t];              s_kh[t][1] = s_tmp[2 * t + 1];
    s_kl[t][0] = s_tmp[2 * NCELL + 2 * t];  s_kl[t][1] = s_tmp[2 * NCELL + 2 * t + 1];
  }
#endif

  // ---------------- block-level setup ----------------
  if (t < EDIM) {
    s_vh[t] = v_hi[t]; s_vl[t] = v_lo[t];
    s_bqh[t] = bq[t];  s_bql[t] = low_bq[t];
  }
  s_iw[t]  = init_w[t];
  s_iwl[t] = low_init_w[t];
  if (t < NCELL) s_maskh[t] = high_mask[b * NCELL + t];

  if (t < EDIM) {
    float s = 0.f;
    for (int n = 0; n < NCELL; ++n) {
      float x = cell_context[((size_t)b * NCELL + n) * EDIM + t];
      s_cc[n][t] = x; s += x;
    }
    s_mean[t] = s / 12.0f;
  }
  __syncthreads();
  matvec<128>(W_hc, s_mean, nullptr, b_hc, s_hbh, s_part, t);
  computeK<6>(Wk, bk, &s_cc[0][0], &s_Kh[0][0], t);
  __syncthreads();
  matvec<256>(W_vw, s_iw, s_hbh, b_vw, s_qh, s_part, t);
  if (t < EDIM) s_qbh[t] = s_hbh[t] + b_vw[t];
  __syncthreads();

  float cell_lp = 0.f, cell_rew = 0.f, lastx = 0.f, lasty = 0.f;

  for (int ci = 0; ci < NCELL; ++ci) {
    // ---- high attention scores
    matvec<128>(Wq, s_qh, nullptr, s_bqh, s_qq, s_part, t);
    if (t < 4 * NCELL) {
      int nd = t >> 2, p = t & 3, rot = t & 31;
      float acc = 0.f;
#pragma unroll 4
      for (int i2 = 0; i2 < 32; ++i2) {
        int h = p * 32 + ((i2 + rot) & 31);
        acc = fmaf(s_vh[h], xla_tanh(s_qq[h] + s_Kh[nd][h]), acc);
      }
      acc += __shfl_xor(acc, 1);
      acc += __shfl_xor(acc, 2);
      if (p == 0) s_u[nd] = acc;
    }
    __syncthreads();

    // ---- sample high cell (wave 0)
    if (t < 64) {
      float logit = -__builtin_huge_valf(), val = -__builtin_huge_valf();
      if (t < NCELL) {
        float lg = (s_maskh[t] > 0.f) ? -1e9f : 10.0f * xla_tanh(s_u[t]);
        logit = lg;
        uint32_t bits = draw_bits(s_kh[ci][0], s_kh[ci][1],
                                  (uint32_t)(b * NCELL + t), (uint32_t)(NB * NCELL));
        val = lg + bits_to_gumbel(bits);
      }
      int bidx = t;
      float mx = logit;
#pragma unroll
      for (int d = 32; d; d >>= 1) {          // fused argmax + max butterflies
        float oval = __shfl_xor(val, d);
        int   oidx = __shfl_xor(bidx, d);
        float omx  = __shfl_xor(mx, d);
        if (oval > val || (oval == val && oidx < bidx)) { val = oval; bidx = oidx; }
        mx = fmaxf(mx, omx);
      }
      float ex = (t < NCELL) ? expf(logit - mx) : 0.f;
#pragma unroll
      for (int d = 32; d; d >>= 1) ex += __shfl_xor(ex, d);
      float chosen = __shfl(logit, bidx);
      cell_lp += (chosen - mx) - logf(ex);
      if (t == 0) {
        s_idx = bidx;
        s_maskh[bidx] = 1.0f;
        out[OFF_CACT + b * NCELL + ci] = (float)bidx;
      }
    }
    __syncthreads();
    const int cidx = s_idx;

    // ---- next high query
    if (ci == 0)
      matvec<128>(W_vw, &s_cc[cidx][0], s_qbh, nullptr, s_qbh, s_part, t);
    if (ci < NCELL - 1)
      matvec<128>(W_vw + 128 * EDIM, &s_cc[cidx][0], s_qbh, nullptr, s_qh, s_part, t);

    // ---- stage selected cell
    const float* embg = node_context + (((size_t)b * NCELL + cidx) * NNODE) * EDIM;
    if (t < EDIM) {
      float s = 0.f;
      for (int n = 0; n < NNODE; ++n) {
        float x = embg[n * EDIM + t];
        s_emb[n][t] = x; s += x;
      }
      s_mean[t] = s / 40.0f;
    }
    if (t >= 128 && t < 208) {
      int q = t - 128;
      s_coords[q >> 1][q & 1] = original_data[(((size_t)b * NCELL + cidx) * NNODE) * 2 + q];
    }
    if (t >= 208 && t < 208 + NNODE) s_maskl[t - 208] = low_mask[b * NNODE + (t - 208)];
    __syncthreads();
    matvec<128>(low_W_hc, s_mean, nullptr, low_b_hc, s_hbl, s_part, t);
    computeK<20>(low_Wk, low_bk, &s_emb[0][0], &s_Kl[0][0], t);
#if PARTITIONABLE
    if (t < NNODE) tf2x32(s_kl[ci][0], s_kl[ci][1], 0u, (uint32_t)t, s_ks[t][0], s_ks[t][1]);
#else
    if (t < NNODE) {
      uint32_t o0, o1;
      tf2x32(s_kl[ci][0], s_kl[ci][1], (uint32_t)t, (uint32_t)(t + NNODE), o0, o1);
      s_ksp[t] = o0; s_ksp[t + NNODE] = o1;
    }
#endif
    __syncthreads();
#if !PARTITIONABLE
    if (t < NNODE) { s_ks[t][0] = s_ksp[2 * t]; s_ks[t][1] = s_ksp[2 * t + 1]; }
#endif
    matvec<256>(low_W_vw, s_iwl, s_hbl, low_b_vw, s_ql, s_part, t);
    if (t < EDIM) s_qbl[t] = s_hbl[t] + low_b_vw[t];
    __syncthreads();

    // ---------------- low decode: 40 steps ----------------
    float llp = 0.f, rew = 0.f, prevx = 0.f, prevy = 0.f, initx = 0.f, inity = 0.f;
    for (int st = 0; st < NNODE; ++st) {
      MATVEC_REGV(rq0, rq1, rq2, rq3, s_ql, (const float*)nullptr, s_bql, s_qq);
      if (t < 160) {
        int nd = t >> 2, p = t & 3, rot = t & 31;
        float acc = 0.f;
#pragma unroll 4
        for (int i2 = 0; i2 < 32; ++i2) {
          int h = p * 32 + ((i2 + rot) & 31);
          acc = fmaf(s_vl[h], xla_tanh(s_qq[h] + s_Kl[nd][h]), acc);
        }
        acc += __shfl_xor(acc, 1);
        acc += __shfl_xor(acc, 2);
        if (p == 0) s_u[nd] = acc;
      }
      __syncthreads();

      if (t < 64) {
        float logit = -__builtin_huge_valf(), val = -__builtin_huge_valf();
        if (t < NNODE) {
          float lg = (s_maskl[t] > 0.f) ? -1e9f : 10.0f * xla_tanh(s_u[t]);
          logit = lg;
          uint32_t bits = draw_bits(s_ks[st][0], s_ks[st][1],
                                    (uint32_t)(b * NNODE + t), (uint32_t)(NB * NNODE));
          val = lg + bits_to_gumbel(bits);
        }
        int bidx = t;
        float mx = logit;
#pragma unroll
        for (int d = 32; d; d >>= 1) {        // fused argmax + max butterflies
          float oval = __shfl_xor(val, d);
          int   oidx = __shfl_xor(bidx, d);
          float omx  = __shfl_xor(mx, d);
          if (oval > val || (oval == val && oidx < bidx)) { val = oval; bidx = oidx; }
          mx = fmaxf(mx, omx);
        }
        float ex = (t < NNODE) ? expf(logit - mx) : 0.f;
#pragma unroll
        for (int d = 32; d; d >>= 1) ex += __shfl_xor(ex, d);
        float chosen = __shfl(logit, bidx);
        llp += (chosen - mx) - logf(ex);
        float cx = s_coords[bidx][0], cy = s_coords[bidx][1];
        if (st == 0) { initx = cx; inity = cy; }
        else { float dx = cx - prevx, dy = cy - prevy; rew += sqrtf(dx * dx + dy * dy); }
        prevx = cx; prevy = cy;
        if (t == 0) {
          s_idx = bidx;
          s_maskl[bidx] = 1.0f;
          out[OFF_NACT + ((size_t)(b * NCELL + ci)) * NNODE + st] = (float)bidx;
        }
      }
      __syncthreads();
      const int ni = s_idx;
      if (st == 0)
        matvec<128>(low_W_vw, &s_emb[ni][0], s_qbl, nullptr, s_qbl, s_part, t);
      if (st < NNODE - 1)
        MATVEC_REGV(rv0, rv1, rv2, rv3, &s_emb[ni][0], s_qbl, (const float*)nullptr, s_ql);
    }

    // ---- finish cell
    if (t < 64) {
      if (ci > 0) {
        float dx = initx - lastx, dy = inity - lasty;
        cell_rew += sqrtf(dx * dx + dy * dy);
      }
      lastx = prevx; lasty = prevy;
      if (t == 0) {
        out[OFF_NLP + b * NCELL + ci] = llp;
        out[OFF_NRW + b * NCELL + ci] = rew;
      }
    }
  }

  if (t == 0) {
    out[OFF_CLP + b] = cell_lp;
    out[OFF_CRW + b] = cell_rew;
  }
}

extern "C" void kernel_launch(void* const* d_in, const int* in_sizes, int n_in,
                              void* d_out, int out_size, void* d_ws, size_t ws_size,
                              hipStream_t stream) {
  (void)in_sizes; (void)n_in; (void)out_size; (void)d_ws; (void)ws_size;
  decoder_kernel<<<NB, THREADS, 0, stream>>>(
      (const float*)d_in[0],  (const float*)d_in[1],  (const float*)d_in[2],
      (const float*)d_in[3],  (const float*)d_in[4],  (const float*)d_in[5],
      (const float*)d_in[6],  (const float*)d_in[7],  (const float*)d_in[8],
      (const float*)d_in[9],  (const float*)d_in[10], (const float*)d_in[11],
      (const float*)d_in[12], (const float*)d_in[13], (const float*)d_in[14],
      (const float*)d_in[15], (const float*)d_in[16], (const float*)d_in[17],
      (const float*)d_in[18], (const float*)d_in[19], (const float*)d_in[20],
      (const float*)d_in[21], (const float*)d_in[22], (const float*)d_in[23],
      (const float*)d_in[24],
      (float*)d_out);
}